// Round 5
// baseline (14001.996 us; speedup 1.0000x reference)
//
#include <hip/hip_runtime.h>
#include <math.h>

#define HID 512
#define B 64
#define SEQT 1024
#define FUT 16
#define TT (SEQT + FUT)
#define NWG 256
#define TPB 512          // fallback path block size
#define TPB1 1024        // main kernel block size (16 waves, 4/SIMD)
#define NWAVE1 16
#define JPW 2            // hidden units owned per WG = HID/NWG
#define HB (HID * B)     // one h buffer, floats
#define BLOBF 12288      // floats per WG: 4096 (phase1) + 8192 (phase2)

typedef __attribute__((ext_vector_type(2))) float f2;   // v_pk_fma_f32 pairs

__device__ inline f2 dupf(float v) { return (f2){v, v}; }

// ws float layout (main path):
//   [0..511]               barrier block (ints): slot[wg] at int wg (wg<256)
//   [512 .. +2HB)          h1 double buffer  (r18 layout: float4 tile at
//                          [k>>1][b>>1] = {h(k0,b0),h(k0,b1),h(k1,b0),h(k1,b1)})
//   [.. +2HB)              h2 double buffer  (same layout)
//   [.. +NWG*BLOBF)        rearranged weight blobs (per WG) — layout unchanged
//   [.. +SEQT*B)           xT (x transposed to [t][b])
//   [.. +SEQT*NWG*B)       deferred-output partials part[t][wg][b] (defer mode)
#define WS_H1_F   512
#define WS_H2_F   (WS_H1_F + 2 * HB)
#define WS_BLOB_F (WS_H2_F + 2 * HB)
#define WS_XT_F   (WS_BLOB_F + NWG * BLOBF)
#define WS_TOT_F  (WS_XT_F + SEQT * B)
#define WS_PART_F WS_TOT_F
#define WS_TOT2_F (WS_PART_F + (size_t)SEQT * NWG * B)

// r13: publish via atomic EXCHANGE (RMW executes at the coherence point and
// ALLOCATES there), not write-through store.
__device__ inline void pub_store(float* p, float v) {
  (void)__hip_atomic_exchange(p, v, __ATOMIC_RELAXED, __HIP_MEMORY_SCOPE_AGENT);
}

// ---- grid barrier v5 (r8): slot stores + every WG polls all 256 slots ------
// UNCHANGED from the banked r13 kernel (r14/r15 showed sync-structure edits
// are where the unexplained-traffic regressions live).
__device__ inline void gbar5(int* bb, int wg, int bar) {
  __builtin_amdgcn_s_waitcnt(0);   // all threads drain own publishes
  __syncthreads();
  const int tid = threadIdx.x;
  if (tid == 0) {
    __hip_atomic_store(bb + wg, bar, __ATOMIC_RELAXED, __HIP_MEMORY_SCOPE_AGENT);
    __builtin_amdgcn_fence(__ATOMIC_ACQUIRE, "agent");  // pre-spin inv, once
  }
  if (tid < 64) {
    for (;;) {
      int a = __hip_atomic_load(bb + tid,       __ATOMIC_RELAXED, __HIP_MEMORY_SCOPE_AGENT);
      int b = __hip_atomic_load(bb + 64  + tid, __ATOMIC_RELAXED, __HIP_MEMORY_SCOPE_AGENT);
      int c = __hip_atomic_load(bb + 128 + tid, __ATOMIC_RELAXED, __HIP_MEMORY_SCOPE_AGENT);
      int d = __hip_atomic_load(bb + 192 + tid, __ATOMIC_RELAXED, __HIP_MEMORY_SCOPE_AGENT);
      if (__all(a >= bar && b >= bar && c >= bar && d >= bar)) break;
      __builtin_amdgcn_s_sleep(1);
    }
  }
  __syncthreads();  // h loads below stay below
}

// ---------------- prep: zero state, rearrange weights, transpose x -----------
// IDENTICAL to r13 (blob layout [k*8+r] / [k*16+rr] is already k-major).
__global__ void __launch_bounds__(256) prep_ws(
    const float* __restrict__ x,
    const float* __restrict__ U1, const float* __restrict__ W2,
    const float* __restrict__ U2, float* __restrict__ ws)
{
  const int idx = blockIdx.x * blockDim.x + threadIdx.x;
  if (idx < WS_BLOB_F) ws[idx] = 0.0f;         // barrier + h buffers
  {
    const int i2 = idx - WS_BLOB_F;
    if (i2 >= 0 && i2 < NWG * BLOBF) {
      const int wg  = i2 / BLOBF;
      const int off = i2 - wg * BLOBF;
      const int j0  = wg * JPW;
      float v;
      if (off < 4096) {                        // phase1: [k*8 + r] = U1[row(r)][k]
        const int k = off >> 3, r = off & 7;
        const int row = (r >> 1) * HID + j0 + (r & 1);
        v = U1[(size_t)row * HID + k];
      } else {                                 // phase2: [k*16 + rr]
        const int o2 = off - 4096;
        const int k = o2 >> 4, rr = o2 & 15;
        const int r = rr & 7;
        const int row = (r >> 1) * HID + j0 + (r & 1);
        v = (rr < 8) ? W2[(size_t)row * HID + k] : U2[(size_t)row * HID + k];
      }
      ws[WS_BLOB_F + i2] = v;
    }
  }
  {
    const int i3 = idx - WS_XT_F;
    if (i3 >= 0 && i3 < SEQT * B) {
      const int t = i3 >> 6, b = i3 & 63;
      ws[WS_XT_F + i3] = x[(size_t)b * SEQT + t];
    }
  }
}

// -------- persistent 2-layer LSTM: r18 = r13 + lane-level (kh, batch-pair) ---
// LDS-pipe theory (r17 counters): 3328 LDS instr/CU/step at ~6-8 cyc ≈ 70% of
// the 12.2us step; VALU 27%; budget closes. r18 halves per-lane weight reads:
// lane = (kh = lane>>5, bp = lane&31); each lane covers 16 k (its kh half of
// the wave's 32-k chunk) for 2 batches (2bp, 2bp+1) packed in f2 accumulators.
// Same pk-fma count, half the ds_read_b128. No cross-lane fold: red[] gains a
// kh axis and cell-elementwise sums 32 partials. Sync/barrier/blob: unchanged.
__global__ void __launch_bounds__(TPB1, 1) rnn_main(
    const float* __restrict__ W1, const float* __restrict__ bW1,
    const float* __restrict__ bU1,
    const float* __restrict__ bW2, const float* __restrict__ bU2,
    const float* __restrict__ lw, const float* __restrict__ lb,
    float* __restrict__ out,
    int* __restrict__ bb,
    float* __restrict__ h1b, float* __restrict__ h2b,
    const float* __restrict__ wbl, const float* __restrict__ xT,
    float* __restrict__ part, int defer)
{
  __shared__ float wlds[BLOBF];            // 48 KB persistent weight blob
  __shared__ float red[NWAVE1][2][8][B];   // per-(wave,kh) partials, 64 KB
  __shared__ float outred[NWAVE1][B];      // output-head reduction, 4 KB
  __shared__ float c1s[JPW][B], c2s[JPW][B];
  __shared__ float pout[JPW][B];           // per-step output partial staging
  __shared__ float w1c[8], bs1[8], bs2[8], lwc[JPW];

  const int wg   = blockIdx.x;
  const int j0   = wg * JPW;
  const int tid  = threadIdx.x;
  const int lane = tid & 63;
  const int wvu  = __builtin_amdgcn_readfirstlane(tid >> 6);
  const int bp   = lane & 31;           // batch pair: handles b=2bp, 2bp+1
  const int kh   = lane >> 5;           // k half within the wave's 32-k chunk

  // ---- one-time: copy this WG's weight blob into LDS ----
  {
    const float4* gsrc = (const float4*)(wbl + (size_t)wg * BLOBF);
    float4* ldst = (float4*)wlds;
    #pragma unroll
    for (int i = 0; i < BLOBF / 4 / TPB1; ++i)
      ldst[i * TPB1 + tid] = gsrc[i * TPB1 + tid];
  }
  if (tid < JPW * B) { c1s[tid >> 6][tid & 63] = 0.f; c2s[tid >> 6][tid & 63] = 0.f; }
  if (tid < 8) {
    const int g = tid >> 1, jl = tid & 1;
    const int row = g * HID + j0 + jl;
    w1c[tid] = W1[row];
    bs1[tid] = bW1[row] + bU1[row];
    bs2[tid] = bW2[row] + bU2[row];
  }
  if (tid < JPW) lwc[tid] = lw[j0 + tid];
  __syncthreads();

  const float* wl1 = wlds + wvu * 256;          // phase1 weights, this wave
  const float* wl2 = wlds + 4096 + wvu * 512;   // phase2 weights, this wave
  const float lbv = lb[0];

  // h buffer layout (r18): float4 tile h4[kq][bq] with kq=k>>1 (0..255),
  // bq=b>>1 (0..31): {h(2kq,2bq), h(2kq,2bq+1), h(2kq+1,2bq), h(2kq+1,2bq+1)}.
  // Lane (wvu, kh, bp) loads kq = wvu*16 + kh*8 + i, bq = bp, i=0..7:
  //   .xy = f2 over (b0,b1) at even k; .zw = f2 at odd k  (register-adjacent).
  const int kq0 = wvu * 16 + kh * 8;

  float4 H1[8], Q[8];                           // h1 carry + h2old staging
  #pragma unroll
  for (int i = 0; i < 8; ++i) H1[i] = make_float4(0.f, 0.f, 0.f, 0.f);

  int bar = 0;
  for (int t = 0; t < TT; ++t) {
    float*       h1new = h1b + (t & 1) * HB;
    const float* h2old = h2b + ((t + 1) & 1) * HB;
    float*       h2new = h2b + (t & 1) * HB;

    // prefetch x for cell-1 (teacher region)
    float xvpref = 0.f;
    if (tid < JPW * B && t < SEQT) xvpref = xT[(size_t)t * B + (tid & 63)];

    // -------- phase 1: gates1 = U1 h1(t-1), h1(t-1) slice in H1 registers ---
    // Per lane: 16 k (kh half) x 8 rows, batches (2bp, 2bp+1) in f2.
    // Weight reads: 32 ds_read_b128 (was 64). Blob: [k*8 + r], k local 0..31.
    {
      f2 ac0 = {0.f, 0.f}, ac1 = {0.f, 0.f}, ac2 = {0.f, 0.f}, ac3 = {0.f, 0.f};
      f2 ac4 = {0.f, 0.f}, ac5 = {0.f, 0.f}, ac6 = {0.f, 0.f}, ac7 = {0.f, 0.f};
      #pragma unroll
      for (int i = 0; i < 8; ++i) {             // i = k-pair within the 16-k half
        const f2 he = {H1[i].x, H1[i].y};       // even k, batches (b0,b1)
        const f2 ho = {H1[i].z, H1[i].w};       // odd  k
        const float* wp = wl1 + (kh * 16 + 2 * i) * 8;
        {
          const float4 wA = *(const float4*)(wp);       // even k, rows 0-3
          const float4 wB = *(const float4*)(wp + 4);   // even k, rows 4-7
          ac0 = __builtin_elementwise_fma(dupf(wA.x), he, ac0);
          ac1 = __builtin_elementwise_fma(dupf(wA.y), he, ac1);
          ac2 = __builtin_elementwise_fma(dupf(wA.z), he, ac2);
          ac3 = __builtin_elementwise_fma(dupf(wA.w), he, ac3);
          ac4 = __builtin_elementwise_fma(dupf(wB.x), he, ac4);
          ac5 = __builtin_elementwise_fma(dupf(wB.y), he, ac5);
          ac6 = __builtin_elementwise_fma(dupf(wB.z), he, ac6);
          ac7 = __builtin_elementwise_fma(dupf(wB.w), he, ac7);
        }
        {
          const float4 wC = *(const float4*)(wp + 8);   // odd k, rows 0-3
          const float4 wD = *(const float4*)(wp + 12);  // odd k, rows 4-7
          ac0 = __builtin_elementwise_fma(dupf(wC.x), ho, ac0);
          ac1 = __builtin_elementwise_fma(dupf(wC.y), ho, ac1);
          ac2 = __builtin_elementwise_fma(dupf(wC.z), ho, ac2);
          ac3 = __builtin_elementwise_fma(dupf(wC.w), ho, ac3);
          ac4 = __builtin_elementwise_fma(dupf(wD.x), ho, ac4);
          ac5 = __builtin_elementwise_fma(dupf(wD.y), ho, ac5);
          ac6 = __builtin_elementwise_fma(dupf(wD.z), ho, ac6);
          ac7 = __builtin_elementwise_fma(dupf(wD.w), ho, ac7);
        }
      }
      f2* rb = (f2*)(&red[wvu][kh][0][0]);      // row r at rb[r*32 + bp]
      rb[0 * 32 + bp] = ac0; rb[1 * 32 + bp] = ac1;
      rb[2 * 32 + bp] = ac2; rb[3 * 32 + bp] = ac3;
      rb[4 * 32 + bp] = ac4; rb[5 * 32 + bp] = ac5;
      rb[6 * 32 + bp] = ac6; rb[7 * 32 + bp] = ac7;
    }
    __syncthreads();

    // cell-1 elementwise (2 j's x 64 b = 128 threads); sums 32 partials now
    if (tid < JPW * B) {
      const int jl = tid >> 6, b = tid & 63;
      const float xv = (t < SEQT) ? xvpref : out[(size_t)b * TT + (t - 1)];
      float gate[4];
      #pragma unroll
      for (int g = 0; g < 4; ++g) {
        const int r = g * 2 + jl;
        float s = bs1[r] + xv * w1c[r];
        #pragma unroll
        for (int w = 0; w < NWAVE1; ++w) s += red[w][0][r][b] + red[w][1][r][b];
        gate[g] = s;
      }
      const float c = gate[1] * c1s[jl][b] + gate[0] * gate[2];
      c1s[jl][b] = c;
      const int j = j0 + jl;
      // r18 h layout: float idx = (kq*32 + bq)*4 + (k&1)*2 + (b&1)
      pub_store(&h1new[(size_t)((j >> 1) * 32 + (b >> 1)) * 4 + (j & 1) * 2 + (b & 1)],
                gate[3] * tanhf(c));
    }

    ++bar;
    gbar5(bb, wg, bar);

    // non-defer mode only: duty WG computes output head inline
    if (!defer && wg == (t & 127) && t >= 1 && t <= SEQT - 1) {
      const int b = lane;
      const float4* hb2 = (const float4*)h2old + (size_t)(wvu * 16) * 32 + (b >> 1);
      const float* lwp = lw + wvu * 32;
      float p = 0.f;
      #pragma unroll
      for (int ii = 0; ii < 16; ++ii) {
        const float4 v = hb2[ii * 32];
        const float hk0 = (b & 1) ? v.y : v.x;
        const float hk1 = (b & 1) ? v.w : v.z;
        p = fmaf(lwp[2 * ii], hk0, p);
        p = fmaf(lwp[2 * ii + 1], hk1, p);
      }
      outred[wvu][lane] = p;
      __syncthreads();
      if (tid < B) {
        float o = lbv;
        #pragma unroll
        for (int s = 0; s < NWAVE1; ++s) o += outred[s][tid];
        pub_store(&out[(size_t)tid * TT + (t - 1)], o);
      }
      __syncthreads();
    }

    // -------- phase 2: gates2 = W2 h1(t) + U2 h2(t-1) ------------------------
    // H1 <- h1(t) slice (kept for next step's phase 1), Q <- h2(t-1) slice.
    // Weight reads: 64 ds_read_b128 (was 128). Blob: [k*16 + rr], rr<8=W2.
    {
      const float4* pp4 = (const float4*)h1new + (size_t)kq0 * 32 + bp;
      const float4* qq4 = (const float4*)h2old + (size_t)kq0 * 32 + bp;
      #pragma unroll
      for (int i = 0; i < 8; ++i) H1[i] = pp4[i * 32];
      #pragma unroll
      for (int i = 0; i < 8; ++i) Q[i] = qq4[i * 32];
      f2 ac0 = {0.f, 0.f}, ac1 = {0.f, 0.f}, ac2 = {0.f, 0.f}, ac3 = {0.f, 0.f};
      f2 ac4 = {0.f, 0.f}, ac5 = {0.f, 0.f}, ac6 = {0.f, 0.f}, ac7 = {0.f, 0.f};
      #pragma unroll
      for (int i = 0; i < 8; ++i) {
        const f2 h1e = {H1[i].x, H1[i].y};
        const f2 h1o = {H1[i].z, H1[i].w};
        const f2 qe  = {Q[i].x,  Q[i].y};
        const f2 qo  = {Q[i].z,  Q[i].w};
        const float* wp = wl2 + (kh * 16 + 2 * i) * 16;
        {  // even k: W2 rows 0-7, U2 rows 0-7
          const float4 wA = *(const float4*)(wp);
          const float4 wB = *(const float4*)(wp + 4);
          ac0 = __builtin_elementwise_fma(dupf(wA.x), h1e, ac0);
          ac1 = __builtin_elementwise_fma(dupf(wA.y), h1e, ac1);
          ac2 = __builtin_elementwise_fma(dupf(wA.z), h1e, ac2);
          ac3 = __builtin_elementwise_fma(dupf(wA.w), h1e, ac3);
          ac4 = __builtin_elementwise_fma(dupf(wB.x), h1e, ac4);
          ac5 = __builtin_elementwise_fma(dupf(wB.y), h1e, ac5);
          ac6 = __builtin_elementwise_fma(dupf(wB.z), h1e, ac6);
          ac7 = __builtin_elementwise_fma(dupf(wB.w), h1e, ac7);
          const float4 uA = *(const float4*)(wp + 8);
          const float4 uB = *(const float4*)(wp + 12);
          ac0 = __builtin_elementwise_fma(dupf(uA.x), qe, ac0);
          ac1 = __builtin_elementwise_fma(dupf(uA.y), qe, ac1);
          ac2 = __builtin_elementwise_fma(dupf(uA.z), qe, ac2);
          ac3 = __builtin_elementwise_fma(dupf(uA.w), qe, ac3);
          ac4 = __builtin_elementwise_fma(dupf(uB.x), qe, ac4);
          ac5 = __builtin_elementwise_fma(dupf(uB.y), qe, ac5);
          ac6 = __builtin_elementwise_fma(dupf(uB.z), qe, ac6);
          ac7 = __builtin_elementwise_fma(dupf(uB.w), qe, ac7);
        }
        {  // odd k
          const float4 wC = *(const float4*)(wp + 16);
          const float4 wD = *(const float4*)(wp + 20);
          ac0 = __builtin_elementwise_fma(dupf(wC.x), h1o, ac0);
          ac1 = __builtin_elementwise_fma(dupf(wC.y), h1o, ac1);
          ac2 = __builtin_elementwise_fma(dupf(wC.z), h1o, ac2);
          ac3 = __builtin_elementwise_fma(dupf(wC.w), h1o, ac3);
          ac4 = __builtin_elementwise_fma(dupf(wD.x), h1o, ac4);
          ac5 = __builtin_elementwise_fma(dupf(wD.y), h1o, ac5);
          ac6 = __builtin_elementwise_fma(dupf(wD.z), h1o, ac6);
          ac7 = __builtin_elementwise_fma(dupf(wD.w), h1o, ac7);
          const float4 uC = *(const float4*)(wp + 24);
          const float4 uD = *(const float4*)(wp + 28);
          ac0 = __builtin_elementwise_fma(dupf(uC.x), qo, ac0);
          ac1 = __builtin_elementwise_fma(dupf(uC.y), qo, ac1);
          ac2 = __builtin_elementwise_fma(dupf(uC.z), qo, ac2);
          ac3 = __builtin_elementwise_fma(dupf(uC.w), qo, ac3);
          ac4 = __builtin_elementwise_fma(dupf(uD.x), qo, ac4);
          ac5 = __builtin_elementwise_fma(dupf(uD.y), qo, ac5);
          ac6 = __builtin_elementwise_fma(dupf(uD.z), qo, ac6);
          ac7 = __builtin_elementwise_fma(dupf(uD.w), qo, ac7);
        }
      }
      f2* rb = (f2*)(&red[wvu][kh][0][0]);
      rb[0 * 32 + bp] = ac0; rb[1 * 32 + bp] = ac1;
      rb[2 * 32 + bp] = ac2; rb[3 * 32 + bp] = ac3;
      rb[4 * 32 + bp] = ac4; rb[5 * 32 + bp] = ac5;
      rb[6 * 32 + bp] = ac6; rb[7 * 32 + bp] = ac7;
    }
    __syncthreads();

    // cell-2 elementwise
    if (tid < JPW * B) {
      const int jl = tid >> 6, b = tid & 63;
      float gate[4];
      #pragma unroll
      for (int g = 0; g < 4; ++g) {
        const int r = g * 2 + jl;
        float s = bs2[r];
        #pragma unroll
        for (int w = 0; w < NWAVE1; ++w) s += red[w][0][r][b] + red[w][1][r][b];
        gate[g] = s;
      }
      const float c = gate[1] * c2s[jl][b] + gate[0] * gate[2];
      c2s[jl][b] = c;
      const float h2v = gate[3] * tanhf(c);
      const int j = j0 + jl;
      pub_store(&h2new[(size_t)((j >> 1) * 32 + (b >> 1)) * 4 + (j & 1) * 2 + (b & 1)], h2v);
      if (defer && t < SEQT) pout[jl][b] = lwc[jl] * h2v;  // output partial
    }
    __syncthreads();  // protect red[] + publish pout

    // deferred-output partial store: 64 floats/WG/step
    if (defer && t < SEQT && tid < B) {
      pub_store(&part[((size_t)t * NWG + wg) * B + tid],
                pout[0][tid] + pout[1][tid]);
    }

    // Autoregressive region: out(t) must be visible before phase1(t+1)
    if (t >= SEQT - 1) {
      ++bar;
      gbar5(bb, wg, bar);
      if (wg == 0) {
        const int b = lane;
        const float4* hb2 = (const float4*)h2new + (size_t)(wvu * 16) * 32 + (b >> 1);
        const float* lwp = lw + wvu * 32;
        float p = 0.f;
        #pragma unroll
        for (int ii = 0; ii < 16; ++ii) {
          const float4 v = hb2[ii * 32];
          const float hk0 = (b & 1) ? v.y : v.x;
          const float hk1 = (b & 1) ? v.w : v.z;
          p = fmaf(lwp[2 * ii], hk0, p);
          p = fmaf(lwp[2 * ii + 1], hk1, p);
        }
        outred[wvu][lane] = p;
        __syncthreads();
        if (tid < B) {
          float o = lbv;
          #pragma unroll
          for (int s = 0; s < NWAVE1; ++s) o += outred[s][tid];
          pub_store(&out[(size_t)tid * TT + t], o);
        }
        __syncthreads();
      }
      ++bar;
      gbar5(bb, wg, bar);
    }
  }

  // ---- defer mode tail: parallel reduction of output partials (t=0..1022) --
  if (defer) {
    ++bar;
    gbar5(bb, wg, bar);   // all partial stores visible + L2 inv'd
    for (int tt = wg; tt < SEQT - 1; tt += NWG) {
      const float* pp = part + ((size_t)tt * NWG + wvu * 16) * B + lane;
      float s = 0.f;
      #pragma unroll
      for (int i = 0; i < 16; ++i) s += pp[i * B];
      outred[wvu][lane] = s;
      __syncthreads();
      if (tid < B) {
        float o = lbv;
        #pragma unroll
        for (int v = 0; v < NWAVE1; ++v) o += outred[v][tid];
        out[(size_t)tid * TT + tt] = o;
      }
      __syncthreads();
    }
  }
}

// =================== fallback path (round-0 kernel, known correct) ===========
__device__ inline void gbar(int* cnt, int target) {
  __syncthreads();
  if (threadIdx.x == 0) {
    __threadfence();
    __hip_atomic_fetch_add(cnt, 1, __ATOMIC_RELEASE, __HIP_MEMORY_SCOPE_AGENT);
    while (__hip_atomic_load(cnt, __ATOMIC_ACQUIRE, __HIP_MEMORY_SCOPE_AGENT) < target) {
      __builtin_amdgcn_s_sleep(2);
    }
  }
  __syncthreads();
}

__global__ void __launch_bounds__(TPB) zero_ws(float* ws, int n) {
  int i = blockIdx.x * blockDim.x + threadIdx.x;
  if (i < n) ws[i] = 0.0f;
}

__global__ void __launch_bounds__(TPB) rnn_fallback(
    const float* __restrict__ x,
    const float* __restrict__ W1, const float* __restrict__ bW1,
    const float* __restrict__ U1, const float* __restrict__ bU1,
    const float* __restrict__ W2, const float* __restrict__ bW2,
    const float* __restrict__ U2, const float* __restrict__ bU2,
    const float* __restrict__ lw, const float* __restrict__ lb,
    float* out, float* ws)
{
  __shared__ float red[8][8][B];
  __shared__ float outred[8][B];
  __shared__ float c1s[JPW][B], c2s[JPW][B];
  __shared__ float w1c[8], bs1[8], bs2[8];

  int* cnt   = (int*)ws;
  float* h1b = ws + 16;
  float* h2b = h1b + 2 * HB;

  const int wg   = blockIdx.x;
  const int j0   = wg * JPW;
  const int tid  = threadIdx.x;
  const int lane = tid & 63;
  const int wvu  = __builtin_amdgcn_readfirstlane(tid >> 6);
  const int kb   = wvu << 6;

  if (tid < JPW * B) { c1s[tid >> 6][lane] = 0.f; c2s[tid >> 6][lane] = 0.f; }
  if (tid < 8) {
    const int g = tid >> 1, jl = tid & 1;
    const int row = g * HID + j0 + jl;
    w1c[tid] = W1[row];
    bs1[tid] = bW1[row] + bU1[row];
    bs2[tid] = bW2[row] + bU2[row];
  }
  __syncthreads();

  const float* u1p[8]; const float* w2p[8]; const float* u2p[8];
  #pragma unroll
  for (int r = 0; r < 8; ++r) {
    const int row = (r >> 1) * HID + j0 + (r & 1);
    u1p[r] = U1 + (size_t)row * HID + kb;
    w2p[r] = W2 + (size_t)row * HID + kb;
    u2p[r] = U2 + (size_t)row * HID + kb;
  }
  const float lbv = lb[0];

  int bar = 0;
  for (int t = 0; t < TT; ++t) {
    const float* h1old = h1b + ((t + 1) & 1) * HB;
    float*       h1new = h1b + (t & 1) * HB;
    const float* h2old = h2b + ((t + 1) & 1) * HB;
    float*       h2new = h2b + (t & 1) * HB;

    {
      const float* hp = h1old + (size_t)kb * B;
      float a0=0.f,a1=0.f,a2=0.f,a3=0.f,a4=0.f,a5=0.f,a6=0.f,a7=0.f;
      #pragma unroll 8
      for (int k = 0; k < 64; ++k) {
        const float hv = hp[k * B + lane];
        a0 = fmaf(u1p[0][k], hv, a0); a1 = fmaf(u1p[1][k], hv, a1);
        a2 = fmaf(u1p[2][k], hv, a2); a3 = fmaf(u1p[3][k], hv, a3);
        a4 = fmaf(u1p[4][k], hv, a4); a5 = fmaf(u1p[5][k], hv, a5);
        a6 = fmaf(u1p[6][k], hv, a6); a7 = fmaf(u1p[7][k], hv, a7);
      }
      red[wvu][0][lane]=a0; red[wvu][1][lane]=a1; red[wvu][2][lane]=a2; red[wvu][3][lane]=a3;
      red[wvu][4][lane]=a4; red[wvu][5][lane]=a5; red[wvu][6][lane]=a6; red[wvu][7][lane]=a7;
    }
    __syncthreads();

    if (tid < JPW * B) {
      const int jl = tid >> 6, b = tid & 63;
      const float xv = (t < SEQT) ? x[(size_t)b * SEQT + t]
                                  : out[(size_t)b * TT + (t - 1)];
      float gate[4];
      #pragma unroll
      for (int g = 0; g < 4; ++g) {
        const int r = g * 2 + jl;
        float s = bs1[r] + xv * w1c[r];
        #pragma unroll
        for (int w = 0; w < 8; ++w) s += red[w][r][b];
        gate[g] = s;
      }
      const float c = gate[1] * c1s[jl][b] + gate[0] * gate[2];
      c1s[jl][b] = c;
      h1new[(size_t)(j0 + jl) * B + b] = gate[3] * tanhf(c);
    }

    ++bar;
    gbar(cnt, NWG * bar);

    if (wg == 0 && t >= 1 && t <= SEQT - 1) {
      const float* hb2 = h2old + (size_t)(wvu * 64) * B;
      const float* lwp = lw + wvu * 64;
      float p = 0.f;
      #pragma unroll 8
      for (int j = 0; j < 64; ++j) p = fmaf(lwp[j], hb2[j * B + lane], p);
      outred[wvu][lane] = p;
      __syncthreads();
      if (tid < B) {
        float o = lbv;
        #pragma unroll
        for (int s = 0; s < 8; ++s) o += outred[s][tid];
        out[(size_t)tid * TT + (t - 1)] = o;
      }
      __syncthreads();
    }

    {
      const float* h1p = h1new + (size_t)kb * B;
      const float* h2p = h2old + (size_t)kb * B;
      float s0=0.f,s1=0.f,s2=0.f,s3=0.f,s4=0.f,s5=0.f,s6=0.f,s7=0.f;
      float q0=0.f,q1=0.f,q2=0.f,q3=0.f,q4=0.f,q5=0.f,q6=0.f,q7=0.f;
      #pragma unroll 4
      for (int k = 0; k < 64; ++k) {
        const float h1v = h1p[k * B + lane];
        const float h2v = h2p[k * B + lane];
        s0 = fmaf(w2p[0][k], h1v, s0); q0 = fmaf(u2p[0][k], h2v, q0);
        s1 = fmaf(w2p[1][k], h1v, s1); q1 = fmaf(u2p[1][k], h2v, q1);
        s2 = fmaf(w2p[2][k], h1v, s2); q2 = fmaf(u2p[2][k], h2v, q2);
        s3 = fmaf(w2p[3][k], h1v, s3); q3 = fmaf(u2p[3][k], h2v, q3);
        s4 = fmaf(w2p[4][k], h1v, s4); q4 = fmaf(u2p[4][k], h2v, q4);
        s5 = fmaf(w2p[5][k], h1v, s5); q5 = fmaf(u2p[5][k], h2v, q5);
        s6 = fmaf(w2p[6][k], h1v, s6); q6 = fmaf(u2p[6][k], h2v, q6);
        s7 = fmaf(w2p[7][k], h1v, s7); q7 = fmaf(u2p[7][k], h2v, q7);
      }
      red[wvu][0][lane]=s0+q0; red[wvu][1][lane]=s1+q1;
      red[wvu][2][lane]=s2+q2; red[wvu][3][lane]=s3+q3;
      red[wvu][4][lane]=s4+q4; red[wvu][5][lane]=s5+q5;
      red[wvu][6][lane]=s6+q6; red[wvu][7][lane]=s7+q7;
    }
    __syncthreads();

    if (tid < JPW * B) {
      const int jl = tid >> 6, b = tid & 63;
      float gate[4];
      #pragma unroll
      for (int g = 0; g < 4; ++g) {
        const int r = g * 2 + jl;
        float s = bs2[r];
        #pragma unroll
        for (int w = 0; w < 8; ++w) s += red[w][r][b];
        gate[g] = s;
      }
      const float c = gate[1] * c2s[jl][b] + gate[0] * gate[2];
      c2s[jl][b] = c;
      h2new[(size_t)(j0 + jl) * B + b] = gate[3] * tanhf(c);
    }
    __syncthreads();

    if (t >= SEQT - 1) {
      ++bar;
      gbar(cnt, NWG * bar);
      if (wg == 0) {
        const float* hb2 = h2new + (size_t)(wvu * 64) * B;
        const float* lwp = lw + wvu * 64;
        float p = 0.f;
        #pragma unroll 8
        for (int j = 0; j < 64; ++j) p = fmaf(lwp[j], hb2[j * B + lane], p);
        outred[wvu][lane] = p;
        __syncthreads();
        if (tid < B) {
          float o = lbv;
          #pragma unroll
          for (int s = 0; s < 8; ++s) o += outred[s][tid];
          out[(size_t)tid * TT + t] = o;
        }
        __syncthreads();
      }
      ++bar;
      gbar(cnt, NWG * bar);
    }
  }
}

extern "C" void kernel_launch(void* const* d_in, const int* in_sizes, int n_in,
                              void* d_out, int out_size, void* d_ws, size_t ws_size,
                              hipStream_t stream) {
  (void)in_sizes; (void)n_in; (void)out_size;
  const float* x   = (const float*)d_in[0];
  const float* W1  = (const float*)d_in[1];
  const float* bW1 = (const float*)d_in[2];
  const float* U1  = (const float*)d_in[3];
  const float* bU1 = (const float*)d_in[4];
  const float* W2  = (const float*)d_in[5];
  const float* bW2 = (const float*)d_in[6];
  const float* U2  = (const float*)d_in[7];
  const float* bU2 = (const float*)d_in[8];
  const float* lw  = (const float*)d_in[9];
  const float* lb  = (const float*)d_in[10];

  float* out = (float*)d_out;
  float* ws  = (float*)d_ws;

  if (ws_size >= (size_t)WS_TOT_F * sizeof(float)) {
    const int defer = (ws_size >= WS_TOT2_F * sizeof(float)) ? 1 : 0;
    prep_ws<<<(WS_TOT_F + 255) / 256, 256, 0, stream>>>(x, U1, W2, U2, ws);
    rnn_main<<<NWG, TPB1, 0, stream>>>(W1, bW1, bU1, bW2, bU2, lw, lb, out,
                                       (int*)ws, ws + WS_H1_F, ws + WS_H2_F,
                                       ws + WS_BLOB_F, ws + WS_XT_F,
                                       ws + WS_PART_F, defer);
  } else {
    const int nzero = 16 + 4 * HID * B;
    zero_ws<<<(nzero + TPB - 1) / TPB, TPB, 0, stream>>>(ws, nzero);
    rnn_fallback<<<NWG, TPB, 0, stream>>>(x, W1, bW1, U1, bU1,
                                          W2, bW2, U2, bU2, lw, lb, out, ws);
  }
}

// Round 6
// 12113.179 us; speedup vs baseline: 1.1559x; 1.1559x over previous
//
#include <hip/hip_runtime.h>
#include <math.h>

#define HID 512
#define B 64
#define SEQT 1024
#define FUT 16
#define TT (SEQT + FUT)
#define NWG 256
#define TPB 512          // fallback path block size
#define TPB1 1024        // main kernel block size (16 waves, 4/SIMD)
#define NWAVE1 16
#define JPW 2            // hidden units owned per WG = HID/NWG
#define HB (HID * B)     // one h buffer, floats
#define BLOBF 12288      // floats per WG: 4096 (phase1) + 8192 (phase2)

typedef __attribute__((ext_vector_type(2))) float f2;   // v_pk_fma_f32 pairs

__device__ inline f2 dupf(float v) { return (f2){v, v}; }

// ws float layout (main path) — identical to the banked r13 kernel:
//   [0..511]               barrier block (ints): slot[wg] at int wg (wg<256)
//   [512 .. +2HB)          h1 double buffer  (paired layout: float4 tile at
//                          [k>>1][b>>1] = {h(k0,b0),h(k0,b1),h(k1,b0),h(k1,b1)})
//   [.. +2HB)              h2 double buffer  (same layout)
//   [.. +NWG*BLOBF)        rearranged weight blobs (per WG)
//   [.. +SEQT*B)           xT (x transposed to [t][b])
//   [.. +SEQT*NWG*B)       deferred-output partials part[t][wg][b] (defer mode)
#define WS_H1_F   512
#define WS_H2_F   (WS_H1_F + 2 * HB)
#define WS_BLOB_F (WS_H2_F + 2 * HB)
#define WS_XT_F   (WS_BLOB_F + NWG * BLOBF)
#define WS_TOT_F  (WS_XT_F + SEQT * B)
#define WS_PART_F WS_TOT_F
#define WS_TOT2_F (WS_PART_F + (size_t)SEQT * NWG * B)

// r13: publish via atomic EXCHANGE (RMW executes at the coherence point and
// ALLOCATES there), not write-through store.
__device__ inline void pub_store(float* p, float v) {
  (void)__hip_atomic_exchange(p, v, __ATOMIC_RELAXED, __HIP_MEMORY_SCOPE_AGENT);
}

// ---- grid barrier v5 (r8): slot stores + every WG polls all 256 slots ------
// UNCHANGED from the banked r13 kernel.
__device__ inline void gbar5(int* bb, int wg, int bar) {
  __builtin_amdgcn_s_waitcnt(0);   // all threads drain own publishes
  __syncthreads();
  const int tid = threadIdx.x;
  if (tid == 0) {
    __hip_atomic_store(bb + wg, bar, __ATOMIC_RELAXED, __HIP_MEMORY_SCOPE_AGENT);
    __builtin_amdgcn_fence(__ATOMIC_ACQUIRE, "agent");  // pre-spin inv, once
  }
  if (tid < 64) {
    for (;;) {
      int a = __hip_atomic_load(bb + tid,       __ATOMIC_RELAXED, __HIP_MEMORY_SCOPE_AGENT);
      int b = __hip_atomic_load(bb + 64  + tid, __ATOMIC_RELAXED, __HIP_MEMORY_SCOPE_AGENT);
      int c = __hip_atomic_load(bb + 128 + tid, __ATOMIC_RELAXED, __HIP_MEMORY_SCOPE_AGENT);
      int d = __hip_atomic_load(bb + 192 + tid, __ATOMIC_RELAXED, __HIP_MEMORY_SCOPE_AGENT);
      if (__all(a >= bar && b >= bar && c >= bar && d >= bar)) break;
      __builtin_amdgcn_s_sleep(1);
    }
  }
  __syncthreads();  // h loads below stay below
}

// ---------------- prep: zero state, rearrange weights, transpose x -----------
// IDENTICAL to r13 (blob layout [k*8+r] / [k*16+rr] is already k-major).
__global__ void __launch_bounds__(256) prep_ws(
    const float* __restrict__ x,
    const float* __restrict__ U1, const float* __restrict__ W2,
    const float* __restrict__ U2, float* __restrict__ ws)
{
  const int idx = blockIdx.x * blockDim.x + threadIdx.x;
  if (idx < WS_BLOB_F) ws[idx] = 0.0f;         // barrier + h buffers
  {
    const int i2 = idx - WS_BLOB_F;
    if (i2 >= 0 && i2 < NWG * BLOBF) {
      const int wg  = i2 / BLOBF;
      const int off = i2 - wg * BLOBF;
      const int j0  = wg * JPW;
      float v;
      if (off < 4096) {                        // phase1: [k*8 + r] = U1[row(r)][k]
        const int k = off >> 3, r = off & 7;
        const int row = (r >> 1) * HID + j0 + (r & 1);
        v = U1[(size_t)row * HID + k];
      } else {                                 // phase2: [k*16 + rr]
        const int o2 = off - 4096;
        const int k = o2 >> 4, rr = o2 & 15;
        const int r = rr & 7;
        const int row = (r >> 1) * HID + j0 + (r & 1);
        v = (rr < 8) ? W2[(size_t)row * HID + k] : U2[(size_t)row * HID + k];
      }
      ws[WS_BLOB_F + i2] = v;
    }
  }
  {
    const int i3 = idx - WS_XT_F;
    if (i3 >= 0 && i3 < SEQT * B) {
      const int t = i3 >> 6, b = i3 & 63;
      ws[WS_XT_F + i3] = x[(size_t)b * SEQT + t];
    }
  }
}

// fold a f2 accumulator over the kh halves (lane ^ 32); both halves get sums
#define FOLDK(A) do { (A).x += __shfl_xor((A).x, 32); \
                      (A).y += __shfl_xor((A).y, 32); } while (0)

// -------- persistent 2-layer LSTM: r19 = r13 VALU shape + r18 LDS count ------
// r18 post-mortem: halving ds_read_b128 but dup-ing WEIGHTS per fma added
// ~2x VALU movs -> +20%. r19 keeps row-pairs in the f2 (weights packed, h
// dup'd once per (k,batch)) and REUSES each weight f2 across the two batch
// accumulators. Per lane per step: b128 96 (r13: 192), dups 96 (=r13),
// pk-fma 384 (=r13). Lane = (kh = lane>>5: k-half; bp = lane&31: batch pair
// 2bp, 2bp+1). kh halves folded via shfl_xor(32); kh==0 writes rows 0-3,
// kh==1 rows 4-7 -> red stays [16][8][64], cell sections identical to r13.
// Sync/barrier/blob/prep: identical to r13. h layout: r18's (verified).
__global__ void __launch_bounds__(TPB1, 1) rnn_main(
    const float* __restrict__ W1, const float* __restrict__ bW1,
    const float* __restrict__ bU1,
    const float* __restrict__ bW2, const float* __restrict__ bU2,
    const float* __restrict__ lw, const float* __restrict__ lb,
    float* __restrict__ out,
    int* __restrict__ bb,
    float* __restrict__ h1b, float* __restrict__ h2b,
    const float* __restrict__ wbl, const float* __restrict__ xT,
    float* __restrict__ part, int defer)
{
  __shared__ float wlds[BLOBF];         // 48 KB persistent weight blob
  __shared__ float red[NWAVE1][8][B];   // per-wave partial dots, 32 KB
  __shared__ float outred[NWAVE1][B];   // output-head reduction, 4 KB
  __shared__ float c1s[JPW][B], c2s[JPW][B];
  __shared__ float pout[JPW][B];        // per-step output partial staging
  __shared__ float w1c[8], bs1[8], bs2[8], lwc[JPW];

  const int wg   = blockIdx.x;
  const int j0   = wg * JPW;
  const int tid  = threadIdx.x;
  const int lane = tid & 63;
  const int wvu  = __builtin_amdgcn_readfirstlane(tid >> 6);
  const int bp   = lane & 31;           // batch pair: handles b=2bp, 2bp+1
  const int kh   = lane >> 5;           // k half within the wave's 32-k chunk

  // ---- one-time: copy this WG's weight blob into LDS ----
  {
    const float4* gsrc = (const float4*)(wbl + (size_t)wg * BLOBF);
    float4* ldst = (float4*)wlds;
    #pragma unroll
    for (int i = 0; i < BLOBF / 4 / TPB1; ++i)
      ldst[i * TPB1 + tid] = gsrc[i * TPB1 + tid];
  }
  if (tid < JPW * B) { c1s[tid >> 6][tid & 63] = 0.f; c2s[tid >> 6][tid & 63] = 0.f; }
  if (tid < 8) {
    const int g = tid >> 1, jl = tid & 1;
    const int row = g * HID + j0 + jl;
    w1c[tid] = W1[row];
    bs1[tid] = bW1[row] + bU1[row];
    bs2[tid] = bW2[row] + bU2[row];
  }
  if (tid < JPW) lwc[tid] = lw[j0 + tid];
  __syncthreads();

  const float* wl1 = wlds + wvu * 256;          // phase1 weights, this wave
  const float* wl2 = wlds + 4096 + wvu * 512;   // phase2 weights, this wave
  const float lbv = lb[0];

  // h buffer layout: float4 tile h4[kq][bq], kq=k>>1 (0..255), bq=b>>1 (0..31):
  // {h(2kq,2bq), h(2kq,2bq+1), h(2kq+1,2bq), h(2kq+1,2bq+1)}.
  // Lane (wvu,kh,bp) loads kq = wvu*16 + kh*8 + i, bq = bp (i=0..7):
  //   .x/.y = even k, batches b0/b1 ; .z/.w = odd k.
  const int kq0 = wvu * 16 + kh * 8;

  float4 H1[8], Q[8];                           // h1 carry + h2old staging
  #pragma unroll
  for (int i = 0; i < 8; ++i) H1[i] = make_float4(0.f, 0.f, 0.f, 0.f);

  int bar = 0;
  for (int t = 0; t < TT; ++t) {
    float*       h1new = h1b + (t & 1) * HB;
    const float* h2old = h2b + ((t + 1) & 1) * HB;
    float*       h2new = h2b + (t & 1) * HB;

    // prefetch x for cell-1 (teacher region)
    float xvpref = 0.f;
    if (tid < JPW * B && t < SEQT) xvpref = xT[(size_t)t * B + (tid & 63)];

    // -------- phase 1: gates1 = U1 h1(t-1), h1(t-1) slice in H1 registers ---
    // Per lane: 16 k (kh half) x 8 rows x 2 batches. 32 b128, 32 dups, 128 fma.
    {
      f2 a01_0 = {0,0}, a23_0 = {0,0}, a45_0 = {0,0}, a67_0 = {0,0};  // batch b0
      f2 a01_1 = {0,0}, a23_1 = {0,0}, a45_1 = {0,0}, a67_1 = {0,0};  // batch b1
      #pragma unroll
      for (int i = 0; i < 8; ++i) {             // i = k-pair in this 16-k half
        const float* wp = wl1 + (kh * 16 + 2 * i) * 8;
        {  // even k
          const float4 wA = *(const float4*)(wp);       // rows 0-3
          const float4 wB = *(const float4*)(wp + 4);   // rows 4-7
          const f2 w01 = {wA.x, wA.y}, w23 = {wA.z, wA.w};
          const f2 w45 = {wB.x, wB.y}, w67 = {wB.z, wB.w};
          const f2 hb0 = dupf(H1[i].x), hb1 = dupf(H1[i].y);
          a01_0 = __builtin_elementwise_fma(w01, hb0, a01_0);
          a23_0 = __builtin_elementwise_fma(w23, hb0, a23_0);
          a45_0 = __builtin_elementwise_fma(w45, hb0, a45_0);
          a67_0 = __builtin_elementwise_fma(w67, hb0, a67_0);
          a01_1 = __builtin_elementwise_fma(w01, hb1, a01_1);
          a23_1 = __builtin_elementwise_fma(w23, hb1, a23_1);
          a45_1 = __builtin_elementwise_fma(w45, hb1, a45_1);
          a67_1 = __builtin_elementwise_fma(w67, hb1, a67_1);
        }
        {  // odd k
          const float4 wC = *(const float4*)(wp + 8);
          const float4 wD = *(const float4*)(wp + 12);
          const f2 w01 = {wC.x, wC.y}, w23 = {wC.z, wC.w};
          const f2 w45 = {wD.x, wD.y}, w67 = {wD.z, wD.w};
          const f2 hb0 = dupf(H1[i].z), hb1 = dupf(H1[i].w);
          a01_0 = __builtin_elementwise_fma(w01, hb0, a01_0);
          a23_0 = __builtin_elementwise_fma(w23, hb0, a23_0);
          a45_0 = __builtin_elementwise_fma(w45, hb0, a45_0);
          a67_0 = __builtin_elementwise_fma(w67, hb0, a67_0);
          a01_1 = __builtin_elementwise_fma(w01, hb1, a01_1);
          a23_1 = __builtin_elementwise_fma(w23, hb1, a23_1);
          a45_1 = __builtin_elementwise_fma(w45, hb1, a45_1);
          a67_1 = __builtin_elementwise_fma(w67, hb1, a67_1);
        }
      }
      FOLDK(a01_0); FOLDK(a23_0); FOLDK(a45_0); FOLDK(a67_0);
      FOLDK(a01_1); FOLDK(a23_1); FOLDK(a45_1); FOLDK(a67_1);
      const int b0 = 2 * bp, b1 = 2 * bp + 1;
      if (kh == 0) {     // rows 0-3, both batches (8 writes)
        red[wvu][0][b0] = a01_0.x; red[wvu][1][b0] = a01_0.y;
        red[wvu][2][b0] = a23_0.x; red[wvu][3][b0] = a23_0.y;
        red[wvu][0][b1] = a01_1.x; red[wvu][1][b1] = a01_1.y;
        red[wvu][2][b1] = a23_1.x; red[wvu][3][b1] = a23_1.y;
      } else {           // rows 4-7
        red[wvu][4][b0] = a45_0.x; red[wvu][5][b0] = a45_0.y;
        red[wvu][6][b0] = a67_0.x; red[wvu][7][b0] = a67_0.y;
        red[wvu][4][b1] = a45_1.x; red[wvu][5][b1] = a45_1.y;
        red[wvu][6][b1] = a67_1.x; red[wvu][7][b1] = a67_1.y;
      }
    }
    __syncthreads();

    // cell-1 elementwise (2 j's x 64 b = 128 threads) — identical to r13
    if (tid < JPW * B) {
      const int jl = tid >> 6, b = tid & 63;
      const float xv = (t < SEQT) ? xvpref : out[(size_t)b * TT + (t - 1)];
      float gate[4];
      #pragma unroll
      for (int g = 0; g < 4; ++g) {
        const int r = g * 2 + jl;
        float s = bs1[r] + xv * w1c[r];
        #pragma unroll
        for (int w = 0; w < NWAVE1; ++w) s += red[w][r][b];
        gate[g] = s;
      }
      const float c = gate[1] * c1s[jl][b] + gate[0] * gate[2];
      c1s[jl][b] = c;
      const int j = j0 + jl;
      // paired h layout: float idx = ((j>>1)*32 + (b>>1))*4 + (j&1)*2 + (b&1)
      pub_store(&h1new[(size_t)((j >> 1) * 32 + (b >> 1)) * 4 + (j & 1) * 2 + (b & 1)],
                gate[3] * tanhf(c));
    }

    ++bar;
    gbar5(bb, wg, bar);

    // non-defer mode only: duty WG computes output head inline (r18-verified)
    if (!defer && wg == (t & 127) && t >= 1 && t <= SEQT - 1) {
      const int b = lane;
      const float4* hb2 = (const float4*)h2old + (size_t)(wvu * 16) * 32 + (b >> 1);
      const float* lwp = lw + wvu * 32;
      float p = 0.f;
      #pragma unroll
      for (int ii = 0; ii < 16; ++ii) {
        const float4 v = hb2[ii * 32];
        const float hk0 = (b & 1) ? v.y : v.x;
        const float hk1 = (b & 1) ? v.w : v.z;
        p = fmaf(lwp[2 * ii], hk0, p);
        p = fmaf(lwp[2 * ii + 1], hk1, p);
      }
      outred[wvu][lane] = p;
      __syncthreads();
      if (tid < B) {
        float o = lbv;
        #pragma unroll
        for (int s = 0; s < NWAVE1; ++s) o += outred[s][tid];
        pub_store(&out[(size_t)tid * TT + (t - 1)], o);
      }
      __syncthreads();
    }

    // -------- phase 2: gates2 = W2 h1(t) + U2 h2(t-1) ------------------------
    // H1 <- h1(t) slice (kept for next step's phase 1), Q <- h2(t-1) slice.
    // Per lane: 64 b128, 64 dups, 256 fma.
    {
      const float4* pp4 = (const float4*)h1new + (size_t)kq0 * 32 + bp;
      const float4* qq4 = (const float4*)h2old + (size_t)kq0 * 32 + bp;
      #pragma unroll
      for (int i = 0; i < 8; ++i) H1[i] = pp4[i * 32];
      #pragma unroll
      for (int i = 0; i < 8; ++i) Q[i] = qq4[i * 32];
      f2 a01_0 = {0,0}, a23_0 = {0,0}, a45_0 = {0,0}, a67_0 = {0,0};
      f2 a01_1 = {0,0}, a23_1 = {0,0}, a45_1 = {0,0}, a67_1 = {0,0};
      #pragma unroll
      for (int i = 0; i < 8; ++i) {
        const float* wp = wl2 + (kh * 16 + 2 * i) * 16;
        {  // even k: W2 rows 0-7 then U2 rows 0-7
          const float4 wA = *(const float4*)(wp);
          const float4 wB = *(const float4*)(wp + 4);
          const f2 w01 = {wA.x, wA.y}, w23 = {wA.z, wA.w};
          const f2 w45 = {wB.x, wB.y}, w67 = {wB.z, wB.w};
          const f2 hb0 = dupf(H1[i].x), hb1 = dupf(H1[i].y);
          a01_0 = __builtin_elementwise_fma(w01, hb0, a01_0);
          a23_0 = __builtin_elementwise_fma(w23, hb0, a23_0);
          a45_0 = __builtin_elementwise_fma(w45, hb0, a45_0);
          a67_0 = __builtin_elementwise_fma(w67, hb0, a67_0);
          a01_1 = __builtin_elementwise_fma(w01, hb1, a01_1);
          a23_1 = __builtin_elementwise_fma(w23, hb1, a23_1);
          a45_1 = __builtin_elementwise_fma(w45, hb1, a45_1);
          a67_1 = __builtin_elementwise_fma(w67, hb1, a67_1);
          const float4 uA = *(const float4*)(wp + 8);
          const float4 uB = *(const float4*)(wp + 12);
          const f2 u01 = {uA.x, uA.y}, u23 = {uA.z, uA.w};
          const f2 u45 = {uB.x, uB.y}, u67 = {uB.z, uB.w};
          const f2 qb0 = dupf(Q[i].x), qb1 = dupf(Q[i].y);
          a01_0 = __builtin_elementwise_fma(u01, qb0, a01_0);
          a23_0 = __builtin_elementwise_fma(u23, qb0, a23_0);
          a45_0 = __builtin_elementwise_fma(u45, qb0, a45_0);
          a67_0 = __builtin_elementwise_fma(u67, qb0, a67_0);
          a01_1 = __builtin_elementwise_fma(u01, qb1, a01_1);
          a23_1 = __builtin_elementwise_fma(u23, qb1, a23_1);
          a45_1 = __builtin_elementwise_fma(u45, qb1, a45_1);
          a67_1 = __builtin_elementwise_fma(u67, qb1, a67_1);
        }
        {  // odd k
          const float4 wC = *(const float4*)(wp + 16);
          const float4 wD = *(const float4*)(wp + 20);
          const f2 w01 = {wC.x, wC.y}, w23 = {wC.z, wC.w};
          const f2 w45 = {wD.x, wD.y}, w67 = {wD.z, wD.w};
          const f2 hb0 = dupf(H1[i].z), hb1 = dupf(H1[i].w);
          a01_0 = __builtin_elementwise_fma(w01, hb0, a01_0);
          a23_0 = __builtin_elementwise_fma(w23, hb0, a23_0);
          a45_0 = __builtin_elementwise_fma(w45, hb0, a45_0);
          a67_0 = __builtin_elementwise_fma(w67, hb0, a67_0);
          a01_1 = __builtin_elementwise_fma(w01, hb1, a01_1);
          a23_1 = __builtin_elementwise_fma(w23, hb1, a23_1);
          a45_1 = __builtin_elementwise_fma(w45, hb1, a45_1);
          a67_1 = __builtin_elementwise_fma(w67, hb1, a67_1);
          const float4 uC = *(const float4*)(wp + 24);
          const float4 uD = *(const float4*)(wp + 28);
          const f2 u01 = {uC.x, uC.y}, u23 = {uC.z, uC.w};
          const f2 u45 = {uD.x, uD.y}, u67 = {uD.z, uD.w};
          const f2 qb0 = dupf(Q[i].z), qb1 = dupf(Q[i].w);
          a01_0 = __builtin_elementwise_fma(u01, qb0, a01_0);
          a23_0 = __builtin_elementwise_fma(u23, qb0, a23_0);
          a45_0 = __builtin_elementwise_fma(u45, qb0, a45_0);
          a67_0 = __builtin_elementwise_fma(u67, qb0, a67_0);
          a01_1 = __builtin_elementwise_fma(u01, qb1, a01_1);
          a23_1 = __builtin_elementwise_fma(u23, qb1, a23_1);
          a45_1 = __builtin_elementwise_fma(u45, qb1, a45_1);
          a67_1 = __builtin_elementwise_fma(u67, qb1, a67_1);
        }
      }
      FOLDK(a01_0); FOLDK(a23_0); FOLDK(a45_0); FOLDK(a67_0);
      FOLDK(a01_1); FOLDK(a23_1); FOLDK(a45_1); FOLDK(a67_1);
      const int b0 = 2 * bp, b1 = 2 * bp + 1;
      if (kh == 0) {
        red[wvu][0][b0] = a01_0.x; red[wvu][1][b0] = a01_0.y;
        red[wvu][2][b0] = a23_0.x; red[wvu][3][b0] = a23_0.y;
        red[wvu][0][b1] = a01_1.x; red[wvu][1][b1] = a01_1.y;
        red[wvu][2][b1] = a23_1.x; red[wvu][3][b1] = a23_1.y;
      } else {
        red[wvu][4][b0] = a45_0.x; red[wvu][5][b0] = a45_0.y;
        red[wvu][6][b0] = a67_0.x; red[wvu][7][b0] = a67_0.y;
        red[wvu][4][b1] = a45_1.x; red[wvu][5][b1] = a45_1.y;
        red[wvu][6][b1] = a67_1.x; red[wvu][7][b1] = a67_1.y;
      }
    }
    __syncthreads();

    // cell-2 elementwise — identical to r13
    if (tid < JPW * B) {
      const int jl = tid >> 6, b = tid & 63;
      float gate[4];
      #pragma unroll
      for (int g = 0; g < 4; ++g) {
        const int r = g * 2 + jl;
        float s = bs2[r];
        #pragma unroll
        for (int w = 0; w < NWAVE1; ++w) s += red[w][r][b];
        gate[g] = s;
      }
      const float c = gate[1] * c2s[jl][b] + gate[0] * gate[2];
      c2s[jl][b] = c;
      const float h2v = gate[3] * tanhf(c);
      const int j = j0 + jl;
      pub_store(&h2new[(size_t)((j >> 1) * 32 + (b >> 1)) * 4 + (j & 1) * 2 + (b & 1)], h2v);
      if (defer && t < SEQT) pout[jl][b] = lwc[jl] * h2v;  // output partial
    }
    __syncthreads();  // protect red[] + publish pout

    // deferred-output partial store: 64 floats/WG/step
    if (defer && t < SEQT && tid < B) {
      pub_store(&part[((size_t)t * NWG + wg) * B + tid],
                pout[0][tid] + pout[1][tid]);
    }

    // Autoregressive region: out(t) must be visible before phase1(t+1)
    if (t >= SEQT - 1) {
      ++bar;
      gbar5(bb, wg, bar);
      if (wg == 0) {
        const int b = lane;
        const float4* hb2 = (const float4*)h2new + (size_t)(wvu * 16) * 32 + (b >> 1);
        const float* lwp = lw + wvu * 32;
        float p = 0.f;
        #pragma unroll
        for (int ii = 0; ii < 16; ++ii) {
          const float4 v = hb2[ii * 32];
          const float hk0 = (b & 1) ? v.y : v.x;
          const float hk1 = (b & 1) ? v.w : v.z;
          p = fmaf(lwp[2 * ii], hk0, p);
          p = fmaf(lwp[2 * ii + 1], hk1, p);
        }
        outred[wvu][lane] = p;
        __syncthreads();
        if (tid < B) {
          float o = lbv;
          #pragma unroll
          for (int s = 0; s < NWAVE1; ++s) o += outred[s][tid];
          pub_store(&out[(size_t)tid * TT + t], o);
        }
        __syncthreads();
      }
      ++bar;
      gbar5(bb, wg, bar);
    }
  }

  // ---- defer mode tail: parallel reduction of output partials (t=0..1022) --
  if (defer) {
    ++bar;
    gbar5(bb, wg, bar);   // all partial stores visible + L2 inv'd
    for (int tt = wg; tt < SEQT - 1; tt += NWG) {
      const float* pp = part + ((size_t)tt * NWG + wvu * 16) * B + lane;
      float s = 0.f;
      #pragma unroll
      for (int i = 0; i < 16; ++i) s += pp[i * B];
      outred[wvu][lane] = s;
      __syncthreads();
      if (tid < B) {
        float o = lbv;
        #pragma unroll
        for (int v = 0; v < NWAVE1; ++v) o += outred[v][tid];
        out[(size_t)tid * TT + tt] = o;
      }
      __syncthreads();
    }
  }
}

// =================== fallback path (round-0 kernel, known correct) ===========
__device__ inline void gbar(int* cnt, int target) {
  __syncthreads();
  if (threadIdx.x == 0) {
    __threadfence();
    __hip_atomic_fetch_add(cnt, 1, __ATOMIC_RELEASE, __HIP_MEMORY_SCOPE_AGENT);
    while (__hip_atomic_load(cnt, __ATOMIC_ACQUIRE, __HIP_MEMORY_SCOPE_AGENT) < target) {
      __builtin_amdgcn_s_sleep(2);
    }
  }
  __syncthreads();
}

__global__ void __launch_bounds__(TPB) zero_ws(float* ws, int n) {
  int i = blockIdx.x * blockDim.x + threadIdx.x;
  if (i < n) ws[i] = 0.0f;
}

__global__ void __launch_bounds__(TPB) rnn_fallback(
    const float* __restrict__ x,
    const float* __restrict__ W1, const float* __restrict__ bW1,
    const float* __restrict__ U1, const float* __restrict__ bU1,
    const float* __restrict__ W2, const float* __restrict__ bW2,
    const float* __restrict__ U2, const float* __restrict__ bU2,
    const float* __restrict__ lw, const float* __restrict__ lb,
    float* out, float* ws)
{
  __shared__ float red[8][8][B];
  __shared__ float outred[8][B];
  __shared__ float c1s[JPW][B], c2s[JPW][B];
  __shared__ float w1c[8], bs1[8], bs2[8];

  int* cnt   = (int*)ws;
  float* h1b = ws + 16;
  float* h2b = h1b + 2 * HB;

  const int wg   = blockIdx.x;
  const int j0   = wg * JPW;
  const int tid  = threadIdx.x;
  const int lane = tid & 63;
  const int wvu  = __builtin_amdgcn_readfirstlane(tid >> 6);
  const int kb   = wvu << 6;

  if (tid < JPW * B) { c1s[tid >> 6][lane] = 0.f; c2s[tid >> 6][lane] = 0.f; }
  if (tid < 8) {
    const int g = tid >> 1, jl = tid & 1;
    const int row = g * HID + j0 + jl;
    w1c[tid] = W1[row];
    bs1[tid] = bW1[row] + bU1[row];
    bs2[tid] = bW2[row] + bU2[row];
  }
  __syncthreads();

  const float* u1p[8]; const float* w2p[8]; const float* u2p[8];
  #pragma unroll
  for (int r = 0; r < 8; ++r) {
    const int row = (r >> 1) * HID + j0 + (r & 1);
    u1p[r] = U1 + (size_t)row * HID + kb;
    w2p[r] = W2 + (size_t)row * HID + kb;
    u2p[r] = U2 + (size_t)row * HID + kb;
  }
  const float lbv = lb[0];

  int bar = 0;
  for (int t = 0; t < TT; ++t) {
    const float* h1old = h1b + ((t + 1) & 1) * HB;
    float*       h1new = h1b + (t & 1) * HB;
    const float* h2old = h2b + ((t + 1) & 1) * HB;
    float*       h2new = h2b + (t & 1) * HB;

    {
      const float* hp = h1old + (size_t)kb * B;
      float a0=0.f,a1=0.f,a2=0.f,a3=0.f,a4=0.f,a5=0.f,a6=0.f,a7=0.f;
      #pragma unroll 8
      for (int k = 0; k < 64; ++k) {
        const float hv = hp[k * B + lane];
        a0 = fmaf(u1p[0][k], hv, a0); a1 = fmaf(u1p[1][k], hv, a1);
        a2 = fmaf(u1p[2][k], hv, a2); a3 = fmaf(u1p[3][k], hv, a3);
        a4 = fmaf(u1p[4][k], hv, a4); a5 = fmaf(u1p[5][k], hv, a5);
        a6 = fmaf(u1p[6][k], hv, a6); a7 = fmaf(u1p[7][k], hv, a7);
      }
      red[wvu][0][lane]=a0; red[wvu][1][lane]=a1; red[wvu][2][lane]=a2; red[wvu][3][lane]=a3;
      red[wvu][4][lane]=a4; red[wvu][5][lane]=a5; red[wvu][6][lane]=a6; red[wvu][7][lane]=a7;
    }
    __syncthreads();

    if (tid < JPW * B) {
      const int jl = tid >> 6, b = tid & 63;
      const float xv = (t < SEQT) ? x[(size_t)b * SEQT + t]
                                  : out[(size_t)b * TT + (t - 1)];
      float gate[4];
      #pragma unroll
      for (int g = 0; g < 4; ++g) {
        const int r = g * 2 + jl;
        float s = bs1[r] + xv * w1c[r];
        #pragma unroll
        for (int w = 0; w < 8; ++w) s += red[w][r][b];
        gate[g] = s;
      }
      const float c = gate[1] * c1s[jl][b] + gate[0] * gate[2];
      c1s[jl][b] = c;
      h1new[(size_t)(j0 + jl) * B + b] = gate[3] * tanhf(c);
    }

    ++bar;
    gbar(cnt, NWG * bar);

    if (wg == 0 && t >= 1 && t <= SEQT - 1) {
      const float* hb2 = h2old + (size_t)(wvu * 64) * B;
      const float* lwp = lw + wvu * 64;
      float p = 0.f;
      #pragma unroll 8
      for (int j = 0; j < 64; ++j) p = fmaf(lwp[j], hb2[j * B + lane], p);
      outred[wvu][lane] = p;
      __syncthreads();
      if (tid < B) {
        float o = lbv;
        #pragma unroll
        for (int s = 0; s < 8; ++s) o += outred[s][tid];
        out[(size_t)tid * TT + (t - 1)] = o;
      }
      __syncthreads();
    }

    {
      const float* h1p = h1new + (size_t)kb * B;
      const float* h2p = h2old + (size_t)kb * B;
      float s0=0.f,s1=0.f,s2=0.f,s3=0.f,s4=0.f,s5=0.f,s6=0.f,s7=0.f;
      float q0=0.f,q1=0.f,q2=0.f,q3=0.f,q4=0.f,q5=0.f,q6=0.f,q7=0.f;
      #pragma unroll 4
      for (int k = 0; k < 64; ++k) {
        const float h1v = h1p[k * B + lane];
        const float h2v = h2p[k * B + lane];
        s0 = fmaf(w2p[0][k], h1v, s0); q0 = fmaf(u2p[0][k], h2v, q0);
        s1 = fmaf(w2p[1][k], h1v, s1); q1 = fmaf(u2p[1][k], h2v, q1);
        s2 = fmaf(w2p[2][k], h1v, s2); q2 = fmaf(u2p[2][k], h2v, q2);
        s3 = fmaf(w2p[3][k], h1v, s3); q3 = fmaf(u2p[3][k], h2v, q3);
        s4 = fmaf(w2p[4][k], h1v, s4); q4 = fmaf(u2p[4][k], h2v, q4);
        s5 = fmaf(w2p[5][k], h1v, s5); q5 = fmaf(u2p[5][k], h2v, q5);
        s6 = fmaf(w2p[6][k], h1v, s6); q6 = fmaf(u2p[6][k], h2v, q6);
        s7 = fmaf(w2p[7][k], h1v, s7); q7 = fmaf(u2p[7][k], h2v, q7);
      }
      red[wvu][0][lane]=s0+q0; red[wvu][1][lane]=s1+q1;
      red[wvu][2][lane]=s2+q2; red[wvu][3][lane]=s3+q3;
      red[wvu][4][lane]=s4+q4; red[wvu][5][lane]=s5+q5;
      red[wvu][6][lane]=s6+q6; red[wvu][7][lane]=s7+q7;
    }
    __syncthreads();

    if (tid < JPW * B) {
      const int jl = tid >> 6, b = tid & 63;
      float gate[4];
      #pragma unroll
      for (int g = 0; g < 4; ++g) {
        const int r = g * 2 + jl;
        float s = bs2[r];
        #pragma unroll
        for (int w = 0; w < 8; ++w) s += red[w][r][b];
        gate[g] = s;
      }
      const float c = gate[1] * c2s[jl][b] + gate[0] * gate[2];
      c2s[jl][b] = c;
      h2new[(size_t)(j0 + jl) * B + b] = gate[3] * tanhf(c);
    }
    __syncthreads();

    if (t >= SEQT - 1) {
      ++bar;
      gbar(cnt, NWG * bar);
      if (wg == 0) {
        const float* hb2 = h2new + (size_t)(wvu * 64) * B;
        const float* lwp = lw + wvu * 64;
        float p = 0.f;
        #pragma unroll 8
        for (int j = 0; j < 64; ++j) p = fmaf(lwp[j], hb2[j * B + lane], p);
        outred[wvu][lane] = p;
        __syncthreads();
        if (tid < B) {
          float o = lbv;
          #pragma unroll
          for (int s = 0; s < 8; ++s) o += outred[s][tid];
          out[(size_t)tid * TT + t] = o;
        }
        __syncthreads();
      }
      ++bar;
      gbar(cnt, NWG * bar);
    }
  }
}

extern "C" void kernel_launch(void* const* d_in, const int* in_sizes, int n_in,
                              void* d_out, int out_size, void* d_ws, size_t ws_size,
                              hipStream_t stream) {
  (void)in_sizes; (void)n_in; (void)out_size;
  const float* x   = (const float*)d_in[0];
  const float* W1  = (const float*)d_in[1];
  const float* bW1 = (const float*)d_in[2];
  const float* U1  = (const float*)d_in[3];
  const float* bU1 = (const float*)d_in[4];
  const float* W2  = (const float*)d_in[5];
  const float* bW2 = (const float*)d_in[6];
  const float* U2  = (const float*)d_in[7];
  const float* bU2 = (const float*)d_in[8];
  const float* lw  = (const float*)d_in[9];
  const float* lb  = (const float*)d_in[10];

  float* out = (float*)d_out;
  float* ws  = (float*)d_ws;

  if (ws_size >= (size_t)WS_TOT_F * sizeof(float)) {
    const int defer = (ws_size >= WS_TOT2_F * sizeof(float)) ? 1 : 0;
    prep_ws<<<(WS_TOT_F + 255) / 256, 256, 0, stream>>>(x, U1, W2, U2, ws);
    rnn_main<<<NWG, TPB1, 0, stream>>>(W1, bW1, bU1, bW2, bU2, lw, lb, out,
                                       (int*)ws, ws + WS_H1_F, ws + WS_H2_F,
                                       ws + WS_BLOB_F, ws + WS_XT_F,
                                       ws + WS_PART_F, defer);
  } else {
    const int nzero = 16 + 4 * HID * B;
    zero_ws<<<(nzero + TPB - 1) / TPB, TPB, 0, stream>>>(ws, nzero);
    rnn_fallback<<<NWG, TPB, 0, stream>>>(x, W1, bW1, U1, bU1,
                                          W2, bW2, U2, bU2, lw, lb, out, ws);
  }
}

// Round 7
// 11967.950 us; speedup vs baseline: 1.1700x; 1.0121x over previous
//
#include <hip/hip_runtime.h>
#include <math.h>

#define HID 512
#define B 64
#define SEQT 1024
#define FUT 16
#define TT (SEQT + FUT)
#define NWG 256
#define TPB 512          // fallback path block size
#define TPB1 1024        // main kernel block size (16 waves, 4/SIMD)
#define NWAVE1 16
#define JPW 2            // hidden units owned per WG = HID/NWG
#define HB (HID * B)     // one h buffer, floats
#define BLOBF 12288      // floats per WG: 4096 (phase1) + 8192 (phase2)

typedef __attribute__((ext_vector_type(2))) float f2;   // v_pk_fma_f32 pairs

// ws float layout (main path):
//   [0..511]               barrier block (ints): slot[wg] at int wg (wg<256)
//   [512 .. +2HB)          h1 double buffer  (float4 tiles: h4[k>>2][b][k&3])
//   [.. +2HB)              h2 double buffer  (same layout)
//   [.. +NWG*BLOBF)        rearranged weight blobs (per WG)
//   [.. +SEQT*B)           xT (x transposed to [t][b])
//   [.. +SEQT*NWG*B)       deferred-output partials part[t][wg][b] (defer mode)
#define WS_H1_F   512
#define WS_H2_F   (WS_H1_F + 2 * HB)
#define WS_BLOB_F (WS_H2_F + 2 * HB)
#define WS_XT_F   (WS_BLOB_F + NWG * BLOBF)
#define WS_TOT_F  (WS_XT_F + SEQT * B)
#define WS_PART_F WS_TOT_F
#define WS_TOT2_F (WS_PART_F + (size_t)SEQT * NWG * B)

// r13: publish via atomic EXCHANGE (RMW executes at the coherence point and
// ALLOCATES there), not write-through store (which is memory-side
// no-allocate -> h round-tripped HBM every step in r6-r12).
__device__ inline void pub_store(float* p, float v) {
  (void)__hip_atomic_exchange(p, v, __ATOMIC_RELAXED, __HIP_MEMORY_SCOPE_AGENT);
}

// ---- grid barrier v5 (r8) + r20 spin backoff --------------------------------
// Protocol unchanged (slot stores, relaxed polls, ONE pre-spin acquire inv).
// r20 single-variable change: after 3 fast polls, back off to s_sleep(32)
// (~0.85us). Theory: the 256-WG poll herd (65K agent-scope loads/us against
// 16 slot lines, L2-bypassing) congests the MALL queues that also serve the
// critical-path publish ACKs and slot stores. Throttling the herd shortens
// the very RTs the barrier is waiting on.
__device__ inline void gbar5(int* bb, int wg, int bar) {
  __builtin_amdgcn_s_waitcnt(0);   // all threads drain own publishes
  __syncthreads();
  const int tid = threadIdx.x;
  if (tid == 0) {
    __hip_atomic_store(bb + wg, bar, __ATOMIC_RELAXED, __HIP_MEMORY_SCOPE_AGENT);
    __builtin_amdgcn_fence(__ATOMIC_ACQUIRE, "agent");  // pre-spin inv, once
  }
  if (tid < 64) {
    int nspin = 0;
    for (;;) {
      int a = __hip_atomic_load(bb + tid,       __ATOMIC_RELAXED, __HIP_MEMORY_SCOPE_AGENT);
      int b = __hip_atomic_load(bb + 64  + tid, __ATOMIC_RELAXED, __HIP_MEMORY_SCOPE_AGENT);
      int c = __hip_atomic_load(bb + 128 + tid, __ATOMIC_RELAXED, __HIP_MEMORY_SCOPE_AGENT);
      int d = __hip_atomic_load(bb + 192 + tid, __ATOMIC_RELAXED, __HIP_MEMORY_SCOPE_AGENT);
      if (__all(a >= bar && b >= bar && c >= bar && d >= bar)) break;
      ++nspin;
      if (nspin < 4) { __builtin_amdgcn_s_sleep(1); }   // fast path: late arriver
      else           { __builtin_amdgcn_s_sleep(32); }  // herd throttle ~0.85us
    }
  }
  __syncthreads();  // h loads below stay below
}

// ---------------- prep: zero state, rearrange weights, transpose x -----------
__global__ void __launch_bounds__(256) prep_ws(
    const float* __restrict__ x,
    const float* __restrict__ U1, const float* __restrict__ W2,
    const float* __restrict__ U2, float* __restrict__ ws)
{
  const int idx = blockIdx.x * blockDim.x + threadIdx.x;
  if (idx < WS_BLOB_F) ws[idx] = 0.0f;         // barrier + h buffers
  {
    const int i2 = idx - WS_BLOB_F;
    if (i2 >= 0 && i2 < NWG * BLOBF) {
      const int wg  = i2 / BLOBF;
      const int off = i2 - wg * BLOBF;
      const int j0  = wg * JPW;
      float v;
      if (off < 4096) {                        // phase1: [k*8 + r] = U1[row(r)][k]
        const int k = off >> 3, r = off & 7;
        const int row = (r >> 1) * HID + j0 + (r & 1);
        v = U1[(size_t)row * HID + k];
      } else {                                 // phase2: [k*16 + rr]
        const int o2 = off - 4096;
        const int k = o2 >> 4, rr = o2 & 15;
        const int r = rr & 7;
        const int row = (r >> 1) * HID + j0 + (r & 1);
        v = (rr < 8) ? W2[(size_t)row * HID + k] : U2[(size_t)row * HID + k];
      }
      ws[WS_BLOB_F + i2] = v;
    }
  }
  {
    const int i3 = idx - WS_XT_F;
    if (i3 >= 0 && i3 < SEQT * B) {
      const int t = i3 >> 6, b = i3 & 63;
      ws[WS_XT_F + i3] = x[(size_t)b * SEQT + t];
    }
  }
}

// -------- persistent 2-layer LSTM: r10 structure + atomicExch publish --------
// 16 waves/WG (4/SIMD). Wave wvu owns k-chunk [wvu*32, wvu*32+32).
// phase1 uses H1 registers (h1(t-1), carried from last step's phase2 load) ->
// NO global loads before the barrier. phase2 loads H1<-h1(t), Q<-h2(t-1).
__global__ void __launch_bounds__(TPB1, 1) rnn_main(
    const float* __restrict__ W1, const float* __restrict__ bW1,
    const float* __restrict__ bU1,
    const float* __restrict__ bW2, const float* __restrict__ bU2,
    const float* __restrict__ lw, const float* __restrict__ lb,
    float* __restrict__ out,
    int* __restrict__ bb,
    float* __restrict__ h1b, float* __restrict__ h2b,
    const float* __restrict__ wbl, const float* __restrict__ xT,
    float* __restrict__ part, int defer)
{
  __shared__ float wlds[BLOBF];         // 48 KB persistent weight blob
  __shared__ float red[NWAVE1][8][B];   // per-wave partial dots, 32 KB
  __shared__ float outred[NWAVE1][B];   // output-head reduction, 4 KB
  __shared__ float c1s[JPW][B], c2s[JPW][B];
  __shared__ float pout[JPW][B];        // per-step output partial staging
  __shared__ float w1c[8], bs1[8], bs2[8], lwc[JPW];

  const int wg   = blockIdx.x;
  const int j0   = wg * JPW;
  const int tid  = threadIdx.x;
  const int lane = tid & 63;
  const int wvu  = __builtin_amdgcn_readfirstlane(tid >> 6);

  // ---- one-time: copy this WG's weight blob into LDS ----
  {
    const float4* gsrc = (const float4*)(wbl + (size_t)wg * BLOBF);
    float4* ldst = (float4*)wlds;
    #pragma unroll
    for (int i = 0; i < BLOBF / 4 / TPB1; ++i)
      ldst[i * TPB1 + tid] = gsrc[i * TPB1 + tid];
  }
  if (tid < JPW * B) { c1s[tid >> 6][lane] = 0.f; c2s[tid >> 6][lane] = 0.f; }
  if (tid < 8) {
    const int g = tid >> 1, jl = tid & 1;
    const int row = g * HID + j0 + jl;
    w1c[tid] = W1[row];
    bs1[tid] = bW1[row] + bU1[row];
    bs2[tid] = bW2[row] + bU2[row];
  }
  if (tid < JPW) lwc[tid] = lw[j0 + tid];
  __syncthreads();

  const float* wl1 = wlds + wvu * 256;          // phase1 weights, this wave
  const float* wl2 = wlds + 4096 + wvu * 512;   // phase2 weights, this wave
  const float lbv = lb[0];

  float4 H1[8], Q[8];                           // h1 carry + h2old staging
  #pragma unroll
  for (int i = 0; i < 8; ++i) H1[i] = make_float4(0.f, 0.f, 0.f, 0.f);

  int bar = 0;
  for (int t = 0; t < TT; ++t) {
    float*       h1new = h1b + (t & 1) * HB;
    const float* h2old = h2b + ((t + 1) & 1) * HB;
    float*       h2new = h2b + (t & 1) * HB;

    // prefetch x for cell-1 (teacher region)
    float xvpref = 0.f;
    if (tid < JPW * B && t < SEQT) xvpref = xT[(size_t)t * B + lane];

    // -------- phase 1: gates1 = U1 h1(t-1), h1(t-1) in H1 registers ---------
    {
      f2 a01 = {0.f, 0.f}, a23 = {0.f, 0.f}, a45 = {0.f, 0.f}, a67 = {0.f, 0.f};
      #pragma unroll
      for (int c = 0; c < 8; ++c) {             // 8 k-quads in this wave's 32-k
        const float hh[4] = {H1[c].x, H1[c].y, H1[c].z, H1[c].w};
        #pragma unroll
        for (int j = 0; j < 4; ++j) {
          const float4 wA = *(const float4*)(wl1 + c * 32 + j * 8);      // b128
          const float4 wB = *(const float4*)(wl1 + c * 32 + j * 8 + 4);  // b128
          const f2 hs = {hh[j], hh[j]};
          const f2 wA0 = {wA.x, wA.y}, wA1 = {wA.z, wA.w};
          const f2 wB0 = {wB.x, wB.y}, wB1 = {wB.z, wB.w};
          a01 = __builtin_elementwise_fma(wA0, hs, a01);
          a23 = __builtin_elementwise_fma(wA1, hs, a23);
          a45 = __builtin_elementwise_fma(wB0, hs, a45);
          a67 = __builtin_elementwise_fma(wB1, hs, a67);
        }
      }
      red[wvu][0][lane] = a01.x; red[wvu][1][lane] = a01.y;
      red[wvu][2][lane] = a23.x; red[wvu][3][lane] = a23.y;
      red[wvu][4][lane] = a45.x; red[wvu][5][lane] = a45.y;
      red[wvu][6][lane] = a67.x; red[wvu][7][lane] = a67.y;
    }
    __syncthreads();

    // cell-1 elementwise (2 j's x 64 b = 128 threads)
    if (tid < JPW * B) {
      const int jl = tid >> 6, b = tid & 63;
      const float xv = (t < SEQT) ? xvpref : out[(size_t)b * TT + (t - 1)];
      float gate[4];
      #pragma unroll
      for (int g = 0; g < 4; ++g) {
        const int r = g * 2 + jl;
        float s = bs1[r] + xv * w1c[r];
        #pragma unroll
        for (int w = 0; w < NWAVE1; ++w) s += red[w][r][b];
        gate[g] = s;
      }
      const float c = gate[1] * c1s[jl][b] + gate[0] * gate[2];
      c1s[jl][b] = c;
      const int j = j0 + jl;
      pub_store(&h1new[(size_t)(j >> 2) * (B * 4) + b * 4 + (j & 3)],
                gate[3] * tanhf(c));
    }

    ++bar;
    gbar5(bb, wg, bar);

    // non-defer mode only: duty WG computes output head inline
    if (!defer && wg == (t & 127) && t >= 1 && t <= SEQT - 1) {
      const float4* hb2 = (const float4*)h2old + (size_t)(wvu * 8) * B + lane;
      const float4* lw4 = (const float4*)lw + wvu * 8;
      float p = 0.f;
      #pragma unroll
      for (int i = 0; i < 8; ++i) {
        const float4 hv = hb2[i * B];
        const float4 wv = lw4[i];
        p = fmaf(wv.x, hv.x, p); p = fmaf(wv.y, hv.y, p);
        p = fmaf(wv.z, hv.z, p); p = fmaf(wv.w, hv.w, p);
      }
      outred[wvu][lane] = p;
      __syncthreads();
      if (tid < B) {
        float o = lbv;
        #pragma unroll
        for (int s = 0; s < NWAVE1; ++s) o += outred[s][tid];
        pub_store(&out[(size_t)tid * TT + (t - 1)], o);
      }
      __syncthreads();
    }

    // -------- phase 2: gates2 = W2 h1(t) + U2 h2(t-1) ------------------------
    // H1 <- h1(t) (kept for next step's phase 1), Q <- h2(t-1)
    {
      const float4* pp4 = (const float4*)h1new + (size_t)(wvu * 8) * B + lane;
      const float4* qq4 = (const float4*)h2old + (size_t)(wvu * 8) * B + lane;
      #pragma unroll
      for (int i = 0; i < 8; ++i) H1[i] = pp4[i * B];
      #pragma unroll
      for (int i = 0; i < 8; ++i) Q[i] = qq4[i * B];
      f2 a01 = {0.f, 0.f}, a23 = {0.f, 0.f}, a45 = {0.f, 0.f}, a67 = {0.f, 0.f};
      #pragma unroll
      for (int c = 0; c < 8; ++c) {
        const float hp_[4] = {H1[c].x, H1[c].y, H1[c].z, H1[c].w};
        const float hq_[4] = {Q[c].x, Q[c].y, Q[c].z, Q[c].w};
        #pragma unroll
        for (int j = 0; j < 4; ++j) {
          const float4 w0 = *(const float4*)(wl2 + c * 64 + j * 16);       // b128
          const float4 w1 = *(const float4*)(wl2 + c * 64 + j * 16 + 4);   // b128
          const float4 w2 = *(const float4*)(wl2 + c * 64 + j * 16 + 8);   // b128
          const float4 w3 = *(const float4*)(wl2 + c * 64 + j * 16 + 12);  // b128
          const f2 hs1 = {hp_[j], hp_[j]};
          const f2 hs2 = {hq_[j], hq_[j]};
          const f2 w0a = {w0.x, w0.y}, w0b = {w0.z, w0.w};
          const f2 w1a = {w1.x, w1.y}, w1b = {w1.z, w1.w};
          const f2 w2a = {w2.x, w2.y}, w2b = {w2.z, w2.w};
          const f2 w3a = {w3.x, w3.y}, w3b = {w3.z, w3.w};
          a01 = __builtin_elementwise_fma(w0a, hs1, a01);
          a23 = __builtin_elementwise_fma(w0b, hs1, a23);
          a45 = __builtin_elementwise_fma(w1a, hs1, a45);
          a67 = __builtin_elementwise_fma(w1b, hs1, a67);
          a01 = __builtin_elementwise_fma(w2a, hs2, a01);
          a23 = __builtin_elementwise_fma(w2b, hs2, a23);
          a45 = __builtin_elementwise_fma(w3a, hs2, a45);
          a67 = __builtin_elementwise_fma(w3b, hs2, a67);
        }
      }
      red[wvu][0][lane] = a01.x; red[wvu][1][lane] = a01.y;
      red[wvu][2][lane] = a23.x; red[wvu][3][lane] = a23.y;
      red[wvu][4][lane] = a45.x; red[wvu][5][lane] = a45.y;
      red[wvu][6][lane] = a67.x; red[wvu][7][lane] = a67.y;
    }
    __syncthreads();

    // cell-2 elementwise
    if (tid < JPW * B) {
      const int jl = tid >> 6, b = tid & 63;
      float gate[4];
      #pragma unroll
      for (int g = 0; g < 4; ++g) {
        const int r = g * 2 + jl;
        float s = bs2[r];
        #pragma unroll
        for (int w = 0; w < NWAVE1; ++w) s += red[w][r][b];
        gate[g] = s;
      }
      const float c = gate[1] * c2s[jl][b] + gate[0] * gate[2];
      c2s[jl][b] = c;
      const float h2v = gate[3] * tanhf(c);
      const int j = j0 + jl;
      pub_store(&h2new[(size_t)(j >> 2) * (B * 4) + b * 4 + (j & 3)], h2v);
      if (defer && t < SEQT) pout[jl][b] = lwc[jl] * h2v;  // output partial
    }
    __syncthreads();  // protect red[] + publish pout

    // deferred-output partial store: 64 floats/WG/step
    if (defer && t < SEQT && tid < B) {
      pub_store(&part[((size_t)t * NWG + wg) * B + tid],
                pout[0][tid] + pout[1][tid]);
    }

    // Autoregressive region: out(t) must be visible before phase1(t+1)
    if (t >= SEQT - 1) {
      ++bar;
      gbar5(bb, wg, bar);
      if (wg == 0) {
        const float4* hb2 = (const float4*)h2new + (size_t)(wvu * 8) * B + lane;
        const float4* lw4 = (const float4*)lw + wvu * 8;
        float p = 0.f;
        #pragma unroll
        for (int i = 0; i < 8; ++i) {
          const float4 hv = hb2[i * B];
          const float4 wv = lw4[i];
          p = fmaf(wv.x, hv.x, p); p = fmaf(wv.y, hv.y, p);
          p = fmaf(wv.z, hv.z, p); p = fmaf(wv.w, hv.w, p);
        }
        outred[wvu][lane] = p;
        __syncthreads();
        if (tid < B) {
          float o = lbv;
          #pragma unroll
          for (int s = 0; s < NWAVE1; ++s) o += outred[s][tid];
          pub_store(&out[(size_t)tid * TT + t], o);
        }
        __syncthreads();
      }
      ++bar;
      gbar5(bb, wg, bar);
    }
  }

  // ---- defer mode tail: parallel reduction of output partials (t=0..1022) --
  if (defer) {
    ++bar;
    gbar5(bb, wg, bar);   // all partial stores visible + L2 inv'd
    for (int tt = wg; tt < SEQT - 1; tt += NWG) {
      const float* pp = part + ((size_t)tt * NWG + wvu * 16) * B + lane;
      float s = 0.f;
      #pragma unroll
      for (int i = 0; i < 16; ++i) s += pp[i * B];
      outred[wvu][lane] = s;
      __syncthreads();
      if (tid < B) {
        float o = lbv;
        #pragma unroll
        for (int v = 0; v < NWAVE1; ++v) o += outred[v][tid];
        out[(size_t)tid * TT + tt] = o;
      }
      __syncthreads();
    }
  }
}

// =================== fallback path (round-0 kernel, known correct) ===========
__device__ inline void gbar(int* cnt, int target) {
  __syncthreads();
  if (threadIdx.x == 0) {
    __threadfence();
    __hip_atomic_fetch_add(cnt, 1, __ATOMIC_RELEASE, __HIP_MEMORY_SCOPE_AGENT);
    while (__hip_atomic_load(cnt, __ATOMIC_ACQUIRE, __HIP_MEMORY_SCOPE_AGENT) < target) {
      __builtin_amdgcn_s_sleep(2);
    }
  }
  __syncthreads();
}

__global__ void __launch_bounds__(TPB) zero_ws(float* ws, int n) {
  int i = blockIdx.x * blockDim.x + threadIdx.x;
  if (i < n) ws[i] = 0.0f;
}

__global__ void __launch_bounds__(TPB) rnn_fallback(
    const float* __restrict__ x,
    const float* __restrict__ W1, const float* __restrict__ bW1,
    const float* __restrict__ U1, const float* __restrict__ bU1,
    const float* __restrict__ W2, const float* __restrict__ bW2,
    const float* __restrict__ U2, const float* __restrict__ bU2,
    const float* __restrict__ lw, const float* __restrict__ lb,
    float* out, float* ws)
{
  __shared__ float red[8][8][B];
  __shared__ float outred[8][B];
  __shared__ float c1s[JPW][B], c2s[JPW][B];
  __shared__ float w1c[8], bs1[8], bs2[8];

  int* cnt   = (int*)ws;
  float* h1b = ws + 16;
  float* h2b = h1b + 2 * HB;

  const int wg   = blockIdx.x;
  const int j0   = wg * JPW;
  const int tid  = threadIdx.x;
  const int lane = tid & 63;
  const int wvu  = __builtin_amdgcn_readfirstlane(tid >> 6);
  const int kb   = wvu << 6;

  if (tid < JPW * B) { c1s[tid >> 6][lane] = 0.f; c2s[tid >> 6][lane] = 0.f; }
  if (tid < 8) {
    const int g = tid >> 1, jl = tid & 1;
    const int row = g * HID + j0 + jl;
    w1c[tid] = W1[row];
    bs1[tid] = bW1[row] + bU1[row];
    bs2[tid] = bW2[row] + bU2[row];
  }
  __syncthreads();

  const float* u1p[8]; const float* w2p[8]; const float* u2p[8];
  #pragma unroll
  for (int r = 0; r < 8; ++r) {
    const int row = (r >> 1) * HID + j0 + (r & 1);
    u1p[r] = U1 + (size_t)row * HID + kb;
    w2p[r] = W2 + (size_t)row * HID + kb;
    u2p[r] = U2 + (size_t)row * HID + kb;
  }
  const float lbv = lb[0];

  int bar = 0;
  for (int t = 0; t < TT; ++t) {
    const float* h1old = h1b + ((t + 1) & 1) * HB;
    float*       h1new = h1b + (t & 1) * HB;
    const float* h2old = h2b + ((t + 1) & 1) * HB;
    float*       h2new = h2b + (t & 1) * HB;

    {
      const float* hp = h1old + (size_t)kb * B;
      float a0=0.f,a1=0.f,a2=0.f,a3=0.f,a4=0.f,a5=0.f,a6=0.f,a7=0.f;
      #pragma unroll 8
      for (int k = 0; k < 64; ++k) {
        const float hv = hp[k * B + lane];
        a0 = fmaf(u1p[0][k], hv, a0); a1 = fmaf(u1p[1][k], hv, a1);
        a2 = fmaf(u1p[2][k], hv, a2); a3 = fmaf(u1p[3][k], hv, a3);
        a4 = fmaf(u1p[4][k], hv, a4); a5 = fmaf(u1p[5][k], hv, a5);
        a6 = fmaf(u1p[6][k], hv, a6); a7 = fmaf(u1p[7][k], hv, a7);
      }
      red[wvu][0][lane]=a0; red[wvu][1][lane]=a1; red[wvu][2][lane]=a2; red[wvu][3][lane]=a3;
      red[wvu][4][lane]=a4; red[wvu][5][lane]=a5; red[wvu][6][lane]=a6; red[wvu][7][lane]=a7;
    }
    __syncthreads();

    if (tid < JPW * B) {
      const int jl = tid >> 6, b = tid & 63;
      const float xv = (t < SEQT) ? x[(size_t)b * SEQT + t]
                                  : out[(size_t)b * TT + (t - 1)];
      float gate[4];
      #pragma unroll
      for (int g = 0; g < 4; ++g) {
        const int r = g * 2 + jl;
        float s = bs1[r] + xv * w1c[r];
        #pragma unroll
        for (int w = 0; w < 8; ++w) s += red[w][r][b];
        gate[g] = s;
      }
      const float c = gate[1] * c1s[jl][b] + gate[0] * gate[2];
      c1s[jl][b] = c;
      h1new[(size_t)(j0 + jl) * B + b] = gate[3] * tanhf(c);
    }

    ++bar;
    gbar(cnt, NWG * bar);

    if (wg == 0 && t >= 1 && t <= SEQT - 1) {
      const float* hb2 = h2old + (size_t)(wvu * 64) * B;
      const float* lwp = lw + wvu * 64;
      float p = 0.f;
      #pragma unroll 8
      for (int j = 0; j < 64; ++j) p = fmaf(lwp[j], hb2[j * B + lane], p);
      outred[wvu][lane] = p;
      __syncthreads();
      if (tid < B) {
        float o = lbv;
        #pragma unroll
        for (int s = 0; s < 8; ++s) o += outred[s][tid];
        out[(size_t)tid * TT + (t - 1)] = o;
      }
      __syncthreads();
    }

    {
      const float* h1p = h1new + (size_t)kb * B;
      const float* h2p = h2old + (size_t)kb * B;
      float s0=0.f,s1=0.f,s2=0.f,s3=0.f,s4=0.f,s5=0.f,s6=0.f,s7=0.f;
      float q0=0.f,q1=0.f,q2=0.f,q3=0.f,q4=0.f,q5=0.f,q6=0.f,q7=0.f;
      #pragma unroll 4
      for (int k = 0; k < 64; ++k) {
        const float h1v = h1p[k * B + lane];
        const float h2v = h2p[k * B + lane];
        s0 = fmaf(w2p[0][k], h1v, s0); q0 = fmaf(u2p[0][k], h2v, q0);
        s1 = fmaf(w2p[1][k], h1v, s1); q1 = fmaf(u2p[1][k], h2v, q1);
        s2 = fmaf(w2p[2][k], h1v, s2); q2 = fmaf(u2p[2][k], h2v, q2);
        s3 = fmaf(w2p[3][k], h1v, s3); q3 = fmaf(u2p[3][k], h2v, q3);
        s4 = fmaf(w2p[4][k], h1v, s4); q4 = fmaf(u2p[4][k], h2v, q4);
        s5 = fmaf(w2p[5][k], h1v, s5); q5 = fmaf(u2p[5][k], h2v, q5);
        s6 = fmaf(w2p[6][k], h1v, s6); q6 = fmaf(u2p[6][k], h2v, q6);
        s7 = fmaf(w2p[7][k], h1v, s7); q7 = fmaf(u2p[7][k], h2v, q7);
      }
      red[wvu][0][lane]=s0+q0; red[wvu][1][lane]=s1+q1;
      red[wvu][2][lane]=s2+q2; red[wvu][3][lane]=s3+q3;
      red[wvu][4][lane]=s4+q4; red[wvu][5][lane]=s5+q5;
      red[wvu][6][lane]=s6+q6; red[wvu][7][lane]=s7+q7;
    }
    __syncthreads();

    if (tid < JPW * B) {
      const int jl = tid >> 6, b = tid & 63;
      float gate[4];
      #pragma unroll
      for (int g = 0; g < 4; ++g) {
        const int r = g * 2 + jl;
        float s = bs2[r];
        #pragma unroll
        for (int w = 0; w < 8; ++w) s += red[w][r][b];
        gate[g] = s;
      }
      const float c = gate[1] * c2s[jl][b] + gate[0] * gate[2];
      c2s[jl][b] = c;
      h2new[(size_t)(j0 + jl) * B + b] = gate[3] * tanhf(c);
    }
    __syncthreads();

    if (t >= SEQT - 1) {
      ++bar;
      gbar(cnt, NWG * bar);
      if (wg == 0) {
        const float* hb2 = h2new + (size_t)(wvu * 64) * B;
        const float* lwp = lw + wvu * 64;
        float p = 0.f;
        #pragma unroll 8
        for (int j = 0; j < 64; ++j) p = fmaf(lwp[j], hb2[j * B + lane], p);
        outred[wvu][lane] = p;
        __syncthreads();
        if (tid < B) {
          float o = lbv;
          #pragma unroll
          for (int s = 0; s < 8; ++s) o += outred[s][tid];
          out[(size_t)tid * TT + t] = o;
        }
        __syncthreads();
      }
      ++bar;
      gbar(cnt, NWG * bar);
    }
  }
}

extern "C" void kernel_launch(void* const* d_in, const int* in_sizes, int n_in,
                              void* d_out, int out_size, void* d_ws, size_t ws_size,
                              hipStream_t stream) {
  (void)in_sizes; (void)n_in; (void)out_size;
  const float* x   = (const float*)d_in[0];
  const float* W1  = (const float*)d_in[1];
  const float* bW1 = (const float*)d_in[2];
  const float* U1  = (const float*)d_in[3];
  const float* bU1 = (const float*)d_in[4];
  const float* W2  = (const float*)d_in[5];
  const float* bW2 = (const float*)d_in[6];
  const float* U2  = (const float*)d_in[7];
  const float* bU2 = (const float*)d_in[8];
  const float* lw  = (const float*)d_in[9];
  const float* lb  = (const float*)d_in[10];

  float* out = (float*)d_out;
  float* ws  = (float*)d_ws;

  if (ws_size >= (size_t)WS_TOT_F * sizeof(float)) {
    const int defer = (ws_size >= WS_TOT2_F * sizeof(float)) ? 1 : 0;
    prep_ws<<<(WS_TOT_F + 255) / 256, 256, 0, stream>>>(x, U1, W2, U2, ws);
    rnn_main<<<NWG, TPB1, 0, stream>>>(W1, bW1, bU1, bW2, bU2, lw, lb, out,
                                       (int*)ws, ws + WS_H1_F, ws + WS_H2_F,
                                       ws + WS_BLOB_F, ws + WS_XT_F,
                                       ws + WS_PART_F, defer);
  } else {
    const int nzero = 16 + 4 * HID * B;
    zero_ws<<<(nzero + TPB - 1) / TPB, TPB, 0, stream>>>(ws, nzero);
    rnn_fallback<<<NWG, TPB, 0, stream>>>(x, W1, bW1, U1, bU1,
                                          W2, bW2, U2, bU2, lw, lb, out, ws);
  }
}

// Round 8
// 11614.854 us; speedup vs baseline: 1.2055x; 1.0304x over previous
//
#include <hip/hip_runtime.h>
#include <math.h>

#define HID 512
#define B 64
#define SEQT 1024
#define FUT 16
#define TT (SEQT + FUT)
#define NWG 256
#define TPB 512          // fallback path block size
#define TPB1 1024        // main kernel block size (16 waves, 4/SIMD)
#define NWAVE1 16
#define JPW 2            // hidden units owned per WG = HID/NWG
#define HB (HID * B)     // one h buffer, floats
#define BLOBF 12288      // floats per WG: 4096 (phase1) + 8192 (phase2)

typedef __attribute__((ext_vector_type(2))) float f2;   // v_pk_fma_f32 pairs

// ws float layout (main path):
//   [0..511]               barrier block (ints): slot[wg] at int wg (wg<256)
//   [512 .. +2HB)          h1 double buffer  (float4 tiles: h4[k>>2][b][k&3])
//   [.. +2HB)              h2 double buffer  (same layout)
//   [.. +NWG*BLOBF)        rearranged weight blobs (per WG)
//   [.. +SEQT*B)           xT (x transposed to [t][b])
//   [.. +SEQT*NWG*B)       deferred-output partials part[t][wg][b] (defer mode)
#define WS_H1_F   512
#define WS_H2_F   (WS_H1_F + 2 * HB)
#define WS_BLOB_F (WS_H2_F + 2 * HB)
#define WS_XT_F   (WS_BLOB_F + NWG * BLOBF)
#define WS_TOT_F  (WS_XT_F + SEQT * B)
#define WS_PART_F WS_TOT_F
#define WS_TOT2_F (WS_PART_F + (size_t)SEQT * NWG * B)

// r13: publish via atomic EXCHANGE (RMW executes at the coherence point and
// ALLOCATES there), not write-through store (which is memory-side
// no-allocate -> h round-tripped HBM every step in r6-r12).
__device__ inline void pub_store(float* p, float v) {
  (void)__hip_atomic_exchange(p, v, __ATOMIC_RELAXED, __HIP_MEMORY_SCOPE_AGENT);
}

// ---- grid barrier v5 (r8): slot stores + every WG polls all 256 slots ------
// r21: EXACT r13/r17 form (s_sleep(1) only). r20's escalating backoff was
// slightly WORSE (+320us): with 256 independent detectors, each WG's release
// is its own detection; a 0.85us sleep quantum makes the worst detector lag
// ~a full quantum per barrier. Fine-grained sleep(1) minimizes that lag.
// Rules from r2-r10: no RMW on the ARRIVAL slots (contended line); relaxed
// spin loads; ONE pre-spin acquire fence (inv) per WG per barrier.
__device__ inline void gbar5(int* bb, int wg, int bar) {
  __builtin_amdgcn_s_waitcnt(0);   // all threads drain own publishes
  __syncthreads();
  const int tid = threadIdx.x;
  if (tid == 0) {
    __hip_atomic_store(bb + wg, bar, __ATOMIC_RELAXED, __HIP_MEMORY_SCOPE_AGENT);
    __builtin_amdgcn_fence(__ATOMIC_ACQUIRE, "agent");  // pre-spin inv, once
  }
  if (tid < 64) {
    for (;;) {
      int a = __hip_atomic_load(bb + tid,       __ATOMIC_RELAXED, __HIP_MEMORY_SCOPE_AGENT);
      int b = __hip_atomic_load(bb + 64  + tid, __ATOMIC_RELAXED, __HIP_MEMORY_SCOPE_AGENT);
      int c = __hip_atomic_load(bb + 128 + tid, __ATOMIC_RELAXED, __HIP_MEMORY_SCOPE_AGENT);
      int d = __hip_atomic_load(bb + 192 + tid, __ATOMIC_RELAXED, __HIP_MEMORY_SCOPE_AGENT);
      if (__all(a >= bar && b >= bar && c >= bar && d >= bar)) break;
      __builtin_amdgcn_s_sleep(1);
    }
  }
  __syncthreads();  // h loads below stay below
}

// ---------------- prep: zero state, rearrange weights, transpose x -----------
__global__ void __launch_bounds__(256) prep_ws(
    const float* __restrict__ x,
    const float* __restrict__ U1, const float* __restrict__ W2,
    const float* __restrict__ U2, float* __restrict__ ws)
{
  const int idx = blockIdx.x * blockDim.x + threadIdx.x;
  if (idx < WS_BLOB_F) ws[idx] = 0.0f;         // barrier + h buffers
  {
    const int i2 = idx - WS_BLOB_F;
    if (i2 >= 0 && i2 < NWG * BLOBF) {
      const int wg  = i2 / BLOBF;
      const int off = i2 - wg * BLOBF;
      const int j0  = wg * JPW;
      float v;
      if (off < 4096) {                        // phase1: [k*8 + r] = U1[row(r)][k]
        const int k = off >> 3, r = off & 7;
        const int row = (r >> 1) * HID + j0 + (r & 1);
        v = U1[(size_t)row * HID + k];
      } else {                                 // phase2: [k*16 + rr]
        const int o2 = off - 4096;
        const int k = o2 >> 4, rr = o2 & 15;
        const int r = rr & 7;
        const int row = (r >> 1) * HID + j0 + (r & 1);
        v = (rr < 8) ? W2[(size_t)row * HID + k] : U2[(size_t)row * HID + k];
      }
      ws[WS_BLOB_F + i2] = v;
    }
  }
  {
    const int i3 = idx - WS_XT_F;
    if (i3 >= 0 && i3 < SEQT * B) {
      const int t = i3 >> 6, b = i3 & 63;
      ws[WS_XT_F + i3] = x[(size_t)b * SEQT + t];
    }
  }
}

// -------- persistent 2-layer LSTM: r10 structure + atomicExch publish --------
// 16 waves/WG (4/SIMD). Wave wvu owns k-chunk [wvu*32, wvu*32+32).
// phase1 uses H1 registers (h1(t-1), carried from last step's phase2 load) ->
// NO global loads before the barrier. phase2 loads H1<-h1(t), Q<-h2(t-1).
__global__ void __launch_bounds__(TPB1, 1) rnn_main(
    const float* __restrict__ W1, const float* __restrict__ bW1,
    const float* __restrict__ bU1,
    const float* __restrict__ bW2, const float* __restrict__ bU2,
    const float* __restrict__ lw, const float* __restrict__ lb,
    float* __restrict__ out,
    int* __restrict__ bb,
    float* __restrict__ h1b, float* __restrict__ h2b,
    const float* __restrict__ wbl, const float* __restrict__ xT,
    float* __restrict__ part, int defer)
{
  __shared__ float wlds[BLOBF];         // 48 KB persistent weight blob
  __shared__ float red[NWAVE1][8][B];   // per-wave partial dots, 32 KB
  __shared__ float outred[NWAVE1][B];   // output-head reduction, 4 KB
  __shared__ float c1s[JPW][B], c2s[JPW][B];
  __shared__ float pout[JPW][B];        // per-step output partial staging
  __shared__ float w1c[8], bs1[8], bs2[8], lwc[JPW];

  const int wg   = blockIdx.x;
  const int j0   = wg * JPW;
  const int tid  = threadIdx.x;
  const int lane = tid & 63;
  const int wvu  = __builtin_amdgcn_readfirstlane(tid >> 6);

  // ---- one-time: copy this WG's weight blob into LDS ----
  {
    const float4* gsrc = (const float4*)(wbl + (size_t)wg * BLOBF);
    float4* ldst = (float4*)wlds;
    #pragma unroll
    for (int i = 0; i < BLOBF / 4 / TPB1; ++i)
      ldst[i * TPB1 + tid] = gsrc[i * TPB1 + tid];
  }
  if (tid < JPW * B) { c1s[tid >> 6][lane] = 0.f; c2s[tid >> 6][lane] = 0.f; }
  if (tid < 8) {
    const int g = tid >> 1, jl = tid & 1;
    const int row = g * HID + j0 + jl;
    w1c[tid] = W1[row];
    bs1[tid] = bW1[row] + bU1[row];
    bs2[tid] = bW2[row] + bU2[row];
  }
  if (tid < JPW) lwc[tid] = lw[j0 + tid];
  __syncthreads();

  const float* wl1 = wlds + wvu * 256;          // phase1 weights, this wave
  const float* wl2 = wlds + 4096 + wvu * 512;   // phase2 weights, this wave
  const float lbv = lb[0];

  float4 H1[8], Q[8];                           // h1 carry + h2old staging
  #pragma unroll
  for (int i = 0; i < 8; ++i) H1[i] = make_float4(0.f, 0.f, 0.f, 0.f);

  int bar = 0;
  for (int t = 0; t < TT; ++t) {
    float*       h1new = h1b + (t & 1) * HB;
    const float* h2old = h2b + ((t + 1) & 1) * HB;
    float*       h2new = h2b + (t & 1) * HB;

    // prefetch x for cell-1 (teacher region)
    float xvpref = 0.f;
    if (tid < JPW * B && t < SEQT) xvpref = xT[(size_t)t * B + lane];

    // -------- phase 1: gates1 = U1 h1(t-1), h1(t-1) in H1 registers ---------
    {
      f2 a01 = {0.f, 0.f}, a23 = {0.f, 0.f}, a45 = {0.f, 0.f}, a67 = {0.f, 0.f};
      #pragma unroll
      for (int c = 0; c < 8; ++c) {             // 8 k-quads in this wave's 32-k
        const float hh[4] = {H1[c].x, H1[c].y, H1[c].z, H1[c].w};
        #pragma unroll
        for (int j = 0; j < 4; ++j) {
          const float4 wA = *(const float4*)(wl1 + c * 32 + j * 8);      // b128
          const float4 wB = *(const float4*)(wl1 + c * 32 + j * 8 + 4);  // b128
          const f2 hs = {hh[j], hh[j]};
          const f2 wA0 = {wA.x, wA.y}, wA1 = {wA.z, wA.w};
          const f2 wB0 = {wB.x, wB.y}, wB1 = {wB.z, wB.w};
          a01 = __builtin_elementwise_fma(wA0, hs, a01);
          a23 = __builtin_elementwise_fma(wA1, hs, a23);
          a45 = __builtin_elementwise_fma(wB0, hs, a45);
          a67 = __builtin_elementwise_fma(wB1, hs, a67);
        }
      }
      red[wvu][0][lane] = a01.x; red[wvu][1][lane] = a01.y;
      red[wvu][2][lane] = a23.x; red[wvu][3][lane] = a23.y;
      red[wvu][4][lane] = a45.x; red[wvu][5][lane] = a45.y;
      red[wvu][6][lane] = a67.x; red[wvu][7][lane] = a67.y;
    }
    __syncthreads();

    // cell-1 elementwise (2 j's x 64 b = 128 threads)
    if (tid < JPW * B) {
      const int jl = tid >> 6, b = tid & 63;
      const float xv = (t < SEQT) ? xvpref : out[(size_t)b * TT + (t - 1)];
      float gate[4];
      #pragma unroll
      for (int g = 0; g < 4; ++g) {
        const int r = g * 2 + jl;
        float s = bs1[r] + xv * w1c[r];
        #pragma unroll
        for (int w = 0; w < NWAVE1; ++w) s += red[w][r][b];
        gate[g] = s;
      }
      const float c = gate[1] * c1s[jl][b] + gate[0] * gate[2];
      c1s[jl][b] = c;
      const int j = j0 + jl;
      pub_store(&h1new[(size_t)(j >> 2) * (B * 4) + b * 4 + (j & 3)],
                gate[3] * tanhf(c));
    }

    ++bar;
    gbar5(bb, wg, bar);

    // non-defer mode only: duty WG computes output head inline
    if (!defer && wg == (t & 127) && t >= 1 && t <= SEQT - 1) {
      const float4* hb2 = (const float4*)h2old + (size_t)(wvu * 8) * B + lane;
      const float4* lw4 = (const float4*)lw + wvu * 8;
      float p = 0.f;
      #pragma unroll
      for (int i = 0; i < 8; ++i) {
        const float4 hv = hb2[i * B];
        const float4 wv = lw4[i];
        p = fmaf(wv.x, hv.x, p); p = fmaf(wv.y, hv.y, p);
        p = fmaf(wv.z, hv.z, p); p = fmaf(wv.w, hv.w, p);
      }
      outred[wvu][lane] = p;
      __syncthreads();
      if (tid < B) {
        float o = lbv;
        #pragma unroll
        for (int s = 0; s < NWAVE1; ++s) o += outred[s][tid];
        pub_store(&out[(size_t)tid * TT + (t - 1)], o);
      }
      __syncthreads();
    }

    // -------- phase 2: gates2 = W2 h1(t) + U2 h2(t-1) ------------------------
    // H1 <- h1(t) (kept for next step's phase 1), Q <- h2(t-1)
    {
      const float4* pp4 = (const float4*)h1new + (size_t)(wvu * 8) * B + lane;
      const float4* qq4 = (const float4*)h2old + (size_t)(wvu * 8) * B + lane;
      #pragma unroll
      for (int i = 0; i < 8; ++i) H1[i] = pp4[i * B];
      #pragma unroll
      for (int i = 0; i < 8; ++i) Q[i] = qq4[i * B];
      f2 a01 = {0.f, 0.f}, a23 = {0.f, 0.f}, a45 = {0.f, 0.f}, a67 = {0.f, 0.f};
      #pragma unroll
      for (int c = 0; c < 8; ++c) {
        const float hp_[4] = {H1[c].x, H1[c].y, H1[c].z, H1[c].w};
        const float hq_[4] = {Q[c].x, Q[c].y, Q[c].z, Q[c].w};
        #pragma unroll
        for (int j = 0; j < 4; ++j) {
          const float4 w0 = *(const float4*)(wl2 + c * 64 + j * 16);       // b128
          const float4 w1 = *(const float4*)(wl2 + c * 64 + j * 16 + 4);   // b128
          const float4 w2 = *(const float4*)(wl2 + c * 64 + j * 16 + 8);   // b128
          const float4 w3 = *(const float4*)(wl2 + c * 64 + j * 16 + 12);  // b128
          const f2 hs1 = {hp_[j], hp_[j]};
          const f2 hs2 = {hq_[j], hq_[j]};
          const f2 w0a = {w0.x, w0.y}, w0b = {w0.z, w0.w};
          const f2 w1a = {w1.x, w1.y}, w1b = {w1.z, w1.w};
          const f2 w2a = {w2.x, w2.y}, w2b = {w2.z, w2.w};
          const f2 w3a = {w3.x, w3.y}, w3b = {w3.z, w3.w};
          a01 = __builtin_elementwise_fma(w0a, hs1, a01);
          a23 = __builtin_elementwise_fma(w0b, hs1, a23);
          a45 = __builtin_elementwise_fma(w1a, hs1, a45);
          a67 = __builtin_elementwise_fma(w1b, hs1, a67);
          a01 = __builtin_elementwise_fma(w2a, hs2, a01);
          a23 = __builtin_elementwise_fma(w2b, hs2, a23);
          a45 = __builtin_elementwise_fma(w3a, hs2, a45);
          a67 = __builtin_elementwise_fma(w3b, hs2, a67);
        }
      }
      red[wvu][0][lane] = a01.x; red[wvu][1][lane] = a01.y;
      red[wvu][2][lane] = a23.x; red[wvu][3][lane] = a23.y;
      red[wvu][4][lane] = a45.x; red[wvu][5][lane] = a45.y;
      red[wvu][6][lane] = a67.x; red[wvu][7][lane] = a67.y;
    }
    __syncthreads();

    // cell-2 elementwise
    if (tid < JPW * B) {
      const int jl = tid >> 6, b = tid & 63;
      float gate[4];
      #pragma unroll
      for (int g = 0; g < 4; ++g) {
        const int r = g * 2 + jl;
        float s = bs2[r];
        #pragma unroll
        for (int w = 0; w < NWAVE1; ++w) s += red[w][r][b];
        gate[g] = s;
      }
      const float c = gate[1] * c2s[jl][b] + gate[0] * gate[2];
      c2s[jl][b] = c;
      const float h2v = gate[3] * tanhf(c);
      const int j = j0 + jl;
      pub_store(&h2new[(size_t)(j >> 2) * (B * 4) + b * 4 + (j & 3)], h2v);
      if (defer && t < SEQT) pout[jl][b] = lwc[jl] * h2v;  // output partial
    }
    __syncthreads();  // protect red[] + publish pout

    // deferred-output partial store: 64 floats/WG/step
    if (defer && t < SEQT && tid < B) {
      pub_store(&part[((size_t)t * NWG + wg) * B + tid],
                pout[0][tid] + pout[1][tid]);
    }

    // Autoregressive region: out(t) must be visible before phase1(t+1)
    if (t >= SEQT - 1) {
      ++bar;
      gbar5(bb, wg, bar);
      if (wg == 0) {
        const float4* hb2 = (const float4*)h2new + (size_t)(wvu * 8) * B + lane;
        const float4* lw4 = (const float4*)lw + wvu * 8;
        float p = 0.f;
        #pragma unroll
        for (int i = 0; i < 8; ++i) {
          const float4 hv = hb2[i * B];
          const float4 wv = lw4[i];
          p = fmaf(wv.x, hv.x, p); p = fmaf(wv.y, hv.y, p);
          p = fmaf(wv.z, hv.z, p); p = fmaf(wv.w, hv.w, p);
        }
        outred[wvu][lane] = p;
        __syncthreads();
        if (tid < B) {
          float o = lbv;
          #pragma unroll
          for (int s = 0; s < NWAVE1; ++s) o += outred[s][tid];
          pub_store(&out[(size_t)tid * TT + t], o);
        }
        __syncthreads();
      }
      ++bar;
      gbar5(bb, wg, bar);
    }
  }

  // ---- defer mode tail: parallel reduction of output partials (t=0..1022) --
  if (defer) {
    ++bar;
    gbar5(bb, wg, bar);   // all partial stores visible + L2 inv'd
    for (int tt = wg; tt < SEQT - 1; tt += NWG) {
      const float* pp = part + ((size_t)tt * NWG + wvu * 16) * B + lane;
      float s = 0.f;
      #pragma unroll
      for (int i = 0; i < 16; ++i) s += pp[i * B];
      outred[wvu][lane] = s;
      __syncthreads();
      if (tid < B) {
        float o = lbv;
        #pragma unroll
        for (int v = 0; v < NWAVE1; ++v) o += outred[v][tid];
        out[(size_t)tid * TT + tt] = o;
      }
      __syncthreads();
    }
  }
}

// =================== fallback path (round-0 kernel, known correct) ===========
__device__ inline void gbar(int* cnt, int target) {
  __syncthreads();
  if (threadIdx.x == 0) {
    __threadfence();
    __hip_atomic_fetch_add(cnt, 1, __ATOMIC_RELEASE, __HIP_MEMORY_SCOPE_AGENT);
    while (__hip_atomic_load(cnt, __ATOMIC_ACQUIRE, __HIP_MEMORY_SCOPE_AGENT) < target) {
      __builtin_amdgcn_s_sleep(2);
    }
  }
  __syncthreads();
}

__global__ void __launch_bounds__(TPB) zero_ws(float* ws, int n) {
  int i = blockIdx.x * blockDim.x + threadIdx.x;
  if (i < n) ws[i] = 0.0f;
}

__global__ void __launch_bounds__(TPB) rnn_fallback(
    const float* __restrict__ x,
    const float* __restrict__ W1, const float* __restrict__ bW1,
    const float* __restrict__ U1, const float* __restrict__ bU1,
    const float* __restrict__ W2, const float* __restrict__ bW2,
    const float* __restrict__ U2, const float* __restrict__ bU2,
    const float* __restrict__ lw, const float* __restrict__ lb,
    float* out, float* ws)
{
  __shared__ float red[8][8][B];
  __shared__ float outred[8][B];
  __shared__ float c1s[JPW][B], c2s[JPW][B];
  __shared__ float w1c[8], bs1[8], bs2[8];

  int* cnt   = (int*)ws;
  float* h1b = ws + 16;
  float* h2b = h1b + 2 * HB;

  const int wg   = blockIdx.x;
  const int j0   = wg * JPW;
  const int tid  = threadIdx.x;
  const int lane = tid & 63;
  const int wvu  = __builtin_amdgcn_readfirstlane(tid >> 6);
  const int kb   = wvu << 6;

  if (tid < JPW * B) { c1s[tid >> 6][lane] = 0.f; c2s[tid >> 6][lane] = 0.f; }
  if (tid < 8) {
    const int g = tid >> 1, jl = tid & 1;
    const int row = g * HID + j0 + jl;
    w1c[tid] = W1[row];
    bs1[tid] = bW1[row] + bU1[row];
    bs2[tid] = bW2[row] + bU2[row];
  }
  __syncthreads();

  const float* u1p[8]; const float* w2p[8]; const float* u2p[8];
  #pragma unroll
  for (int r = 0; r < 8; ++r) {
    const int row = (r >> 1) * HID + j0 + (r & 1);
    u1p[r] = U1 + (size_t)row * HID + kb;
    w2p[r] = W2 + (size_t)row * HID + kb;
    u2p[r] = U2 + (size_t)row * HID + kb;
  }
  const float lbv = lb[0];

  int bar = 0;
  for (int t = 0; t < TT; ++t) {
    const float* h1old = h1b + ((t + 1) & 1) * HB;
    float*       h1new = h1b + (t & 1) * HB;
    const float* h2old = h2b + ((t + 1) & 1) * HB;
    float*       h2new = h2b + (t & 1) * HB;

    {
      const float* hp = h1old + (size_t)kb * B;
      float a0=0.f,a1=0.f,a2=0.f,a3=0.f,a4=0.f,a5=0.f,a6=0.f,a7=0.f;
      #pragma unroll 8
      for (int k = 0; k < 64; ++k) {
        const float hv = hp[k * B + lane];
        a0 = fmaf(u1p[0][k], hv, a0); a1 = fmaf(u1p[1][k], hv, a1);
        a2 = fmaf(u1p[2][k], hv, a2); a3 = fmaf(u1p[3][k], hv, a3);
        a4 = fmaf(u1p[4][k], hv, a4); a5 = fmaf(u1p[5][k], hv, a5);
        a6 = fmaf(u1p[6][k], hv, a6); a7 = fmaf(u1p[7][k], hv, a7);
      }
      red[wvu][0][lane]=a0; red[wvu][1][lane]=a1; red[wvu][2][lane]=a2; red[wvu][3][lane]=a3;
      red[wvu][4][lane]=a4; red[wvu][5][lane]=a5; red[wvu][6][lane]=a6; red[wvu][7][lane]=a7;
    }
    __syncthreads();

    if (tid < JPW * B) {
      const int jl = tid >> 6, b = tid & 63;
      const float xv = (t < SEQT) ? x[(size_t)b * SEQT + t]
                                  : out[(size_t)b * TT + (t - 1)];
      float gate[4];
      #pragma unroll
      for (int g = 0; g < 4; ++g) {
        const int r = g * 2 + jl;
        float s = bs1[r] + xv * w1c[r];
        #pragma unroll
        for (int w = 0; w < 8; ++w) s += red[w][r][b];
        gate[g] = s;
      }
      const float c = gate[1] * c1s[jl][b] + gate[0] * gate[2];
      c1s[jl][b] = c;
      h1new[(size_t)(j0 + jl) * B + b] = gate[3] * tanhf(c);
    }

    ++bar;
    gbar(cnt, NWG * bar);

    if (wg == 0 && t >= 1 && t <= SEQT - 1) {
      const float* hb2 = h2old + (size_t)(wvu * 64) * B;
      const float* lwp = lw + wvu * 64;
      float p = 0.f;
      #pragma unroll 8
      for (int j = 0; j < 64; ++j) p = fmaf(lwp[j], hb2[j * B + lane], p);
      outred[wvu][lane] = p;
      __syncthreads();
      if (tid < B) {
        float o = lbv;
        #pragma unroll
        for (int s = 0; s < 8; ++s) o += outred[s][tid];
        out[(size_t)tid * TT + (t - 1)] = o;
      }
      __syncthreads();
    }

    {
      const float* h1p = h1new + (size_t)kb * B;
      const float* h2p = h2old + (size_t)kb * B;
      float s0=0.f,s1=0.f,s2=0.f,s3=0.f,s4=0.f,s5=0.f,s6=0.f,s7=0.f;
      float q0=0.f,q1=0.f,q2=0.f,q3=0.f,q4=0.f,q5=0.f,q6=0.f,q7=0.f;
      #pragma unroll 4
      for (int k = 0; k < 64; ++k) {
        const float h1v = h1p[k * B + lane];
        const float h2v = h2p[k * B + lane];
        s0 = fmaf(w2p[0][k], h1v, s0); q0 = fmaf(u2p[0][k], h2v, q0);
        s1 = fmaf(w2p[1][k], h1v, s1); q1 = fmaf(u2p[1][k], h2v, q1);
        s2 = fmaf(w2p[2][k], h1v, s2); q2 = fmaf(u2p[2][k], h2v, q2);
        s3 = fmaf(w2p[3][k], h1v, s3); q3 = fmaf(u2p[3][k], h2v, q3);
        s4 = fmaf(w2p[4][k], h1v, s4); q4 = fmaf(u2p[4][k], h2v, q4);
        s5 = fmaf(w2p[5][k], h1v, s5); q5 = fmaf(u2p[5][k], h2v, q5);
        s6 = fmaf(w2p[6][k], h1v, s6); q6 = fmaf(u2p[6][k], h2v, q6);
        s7 = fmaf(w2p[7][k], h1v, s7); q7 = fmaf(u2p[7][k], h2v, q7);
      }
      red[wvu][0][lane]=s0+q0; red[wvu][1][lane]=s1+q1;
      red[wvu][2][lane]=s2+q2; red[wvu][3][lane]=s3+q3;
      red[wvu][4][lane]=s4+q4; red[wvu][5][lane]=s5+q5;
      red[wvu][6][lane]=s6+q6; red[wvu][7][lane]=s7+q7;
    }
    __syncthreads();

    if (tid < JPW * B) {
      const int jl = tid >> 6, b = tid & 63;
      float gate[4];
      #pragma unroll
      for (int g = 0; g < 4; ++g) {
        const int r = g * 2 + jl;
        float s = bs2[r];
        #pragma unroll
        for (int w = 0; w < 8; ++w) s += red[w][r][b];
        gate[g] = s;
      }
      const float c = gate[1] * c2s[jl][b] + gate[0] * gate[2];
      c2s[jl][b] = c;
      h2new[(size_t)(j0 + jl) * B + b] = gate[3] * tanhf(c);
    }
    __syncthreads();

    if (t >= SEQT - 1) {
      ++bar;
      gbar(cnt, NWG * bar);
      if (wg == 0) {
        const float* hb2 = h2new + (size_t)(wvu * 64) * B;
        const float* lwp = lw + wvu * 64;
        float p = 0.f;
        #pragma unroll 8
        for (int j = 0; j < 64; ++j) p = fmaf(lwp[j], hb2[j * B + lane], p);
        outred[wvu][lane] = p;
        __syncthreads();
        if (tid < B) {
          float o = lbv;
          #pragma unroll
          for (int s = 0; s < 8; ++s) o += outred[s][tid];
          out[(size_t)tid * TT + t] = o;
        }
        __syncthreads();
      }
      ++bar;
      gbar(cnt, NWG * bar);
    }
  }
}

extern "C" void kernel_launch(void* const* d_in, const int* in_sizes, int n_in,
                              void* d_out, int out_size, void* d_ws, size_t ws_size,
                              hipStream_t stream) {
  (void)in_sizes; (void)n_in; (void)out_size;
  const float* x   = (const float*)d_in[0];
  const float* W1  = (const float*)d_in[1];
  const float* bW1 = (const float*)d_in[2];
  const float* U1  = (const float*)d_in[3];
  const float* bU1 = (const float*)d_in[4];
  const float* W2  = (const float*)d_in[5];
  const float* bW2 = (const float*)d_in[6];
  const float* U2  = (const float*)d_in[7];
  const float* bU2 = (const float*)d_in[8];
  const float* lw  = (const float*)d_in[9];
  const float* lb  = (const float*)d_in[10];

  float* out = (float*)d_out;
  float* ws  = (float*)d_ws;

  if (ws_size >= (size_t)WS_TOT_F * sizeof(float)) {
    const int defer = (ws_size >= WS_TOT2_F * sizeof(float)) ? 1 : 0;
    prep_ws<<<(WS_TOT_F + 255) / 256, 256, 0, stream>>>(x, U1, W2, U2, ws);
    rnn_main<<<NWG, TPB1, 0, stream>>>(W1, bW1, bU1, bW2, bU2, lw, lb, out,
                                       (int*)ws, ws + WS_H1_F, ws + WS_H2_F,
                                       ws + WS_BLOB_F, ws + WS_XT_F,
                                       ws + WS_PART_F, defer);
  } else {
    const int nzero = 16 + 4 * HID * B;
    zero_ws<<<(nzero + TPB - 1) / TPB, TPB, 0, stream>>>(ws, nzero);
    rnn_fallback<<<NWG, TPB, 0, stream>>>(x, W1, bW1, U1, bU1,
                                          W2, bW2, U2, bU2, lw, lb, out, ws);
  }
}